// Round 3
// baseline (409.397 us; speedup 1.0000x reference)
//
#include <hip/hip_runtime.h>
#include <hip/hip_fp16.h>
#include <math.h>

#define CUTOFF 5.0f
#define H 64
#define FIN 16
#define NLAYERS 3
#define LUTN 2048          // intervals; table has LUTN+1 entries
#define LUTSTRIDE 2052     // padded per-layer stride
#define ASTRIDE 72         // LDS row stride in halves (144B, 16B-aligned)
#define PCHUNK 16          // edge chunks == scatter base partitions
#define WPSMAX 3136        // max packed words per row-split (12.5KB LDS)
#define MEANB 256          // blocks in mean pass (partials rows)
#define LUTB 9             // lut blocks per layer (9*256 >= 2049)

// 1/sqrt(1 + 1e-3)  (BN inference, moving mean 0 / var 1)
#define BN_INV 0.999500374750f

typedef _Float16 h8 __attribute__((ext_vector_type(8)));
typedef _Float16 h2 __attribute__((ext_vector_type(2)));
typedef float f32x4 __attribute__((ext_vector_type(4)));
typedef unsigned int u32x4 __attribute__((ext_vector_type(4)));

__device__ __forceinline__ float softplus_f(float x) {
    return fmaxf(x, 0.f) + __logf(1.f + __expf(-fabsf(x)));
}

// ---- K1: mega setup. Block roles by blockIdx range:
//   [0, nbE)                 embed 4 nodes/block -> h0 fp16
//   [nbE, nbE+27)            LUT: inline wsum/bsum in LDS, 256 entries/block
//   [nbE+27, nbE+39)         weight swizzle Wsw + b2p
__global__ __launch_bounds__(256)
void k_setup(const float* __restrict__ x, const float* __restrict__ emb_W,
             const float* __restrict__ emb_b, _Float16* __restrict__ h0,
             const float* __restrict__ fW1, const float* __restrict__ fb1,
             const float* __restrict__ fW2, const float* __restrict__ fb2,
             const float* __restrict__ iW1, const float* __restrict__ iW2,
             const float* __restrict__ bn_g, const float* __restrict__ bn_b,
             const float* __restrict__ ib2, h8* __restrict__ Wsw,
             float* __restrict__ b2p, float* __restrict__ lut, int N) {
    __shared__ float swsum[64];
    __shared__ float sbsum;
    int b = blockIdx.x;
    int t = threadIdx.x;
    int nbE = (N + 3) / 4;
    if (b < nbE) {
        int lane = t & 63;
        int w = t >> 6;
        int node = b * 4 + w;
        if (node < N) {
            float acc = emb_b[lane];
#pragma unroll
            for (int k = 0; k < FIN; k++) acc += x[node * FIN + k] * emb_W[k * H + lane];
            h0[(size_t)node * H + lane] = (_Float16)acc;
        }
    } else if (b < nbE + NLAYERS * LUTB) {
        int lb = b - nbE;
        int l = lb / LUTB, part = lb % LUTB;
        if (t < 64) {
            float s = 0.f;
            for (int j = 0; j < H; j++) s += fW2[l * H * H + t * H + j];
            swsum[t] = s;
        }
        if (t == 64) {
            float s = 0.f;
            for (int j = 0; j < H; j++) s += fb2[l * H + j];
            sbsum = s;
        }
        __syncthreads();
        int i = part * 256 + t;
        if (i <= LUTN) {
            float d = (float)i * (CUTOFF / (float)LUTN);
            float scaled = d * (2.0f / CUTOFF) - 1.0f;
            float cut = 0.5f * (__cosf(d * (3.14159265358979f / CUTOFF)) + 1.0f);
            if (d > CUTOFF) cut = 0.f;
            float s = 0.f;
            for (int hh = 0; hh < H; hh++) {
                int wi = l * H + hh;
                s += tanhf(scaled * fW1[wi] + fb1[wi]) * swsum[hh];
            }
            lut[l * LUTSTRIDE + i] = cut * (s + sbsum);
        }
    } else {
        int tid = (b - nbE - NLAYERS * LUTB) * 256 + t;
        if (tid < NLAYERS * H)
            b2p[tid] = ib2[tid] * BN_INV * bn_g[tid] + bn_b[tid];
        if (tid < NLAYERS * 2 * 8 * 64) {
            int lane = tid & 63;
            int frag = (tid >> 6) & 7;
            int mat  = (tid >> 9) & 1;
            int l    = tid >> 10;
            int kt = frag >> 2, nt = frag & 3;
            int n = nt * 16 + (lane & 15);
            int k0 = kt * 32 + (lane >> 4) * 8;
            const float* W = (mat ? iW2 : iW1) + l * H * H;
            float scale = mat ? BN_INV * bn_g[l * H + n] : 1.0f;
            h8 v;
#pragma unroll
            for (int j = 0; j < 8; j++) v[j] = (_Float16)(W[(k0 + j) * H + n] * scale);
            Wsw[tid] = v;
        }
    }
}

// LDS histogram + rank. Edge chunk c = e/CHUNK (16 chunks); RS row-split
// blocks per chunk, each counts rows [s*WPS*4, (s+1)*WPS*4) in packed
// byte-per-row LDS counters. atomicAdd's returned byte == within-(chunk,row)
// rank. No global atomics, no global zeroing.
__global__ __launch_bounds__(1024)
void k_hist(const int* __restrict__ ei, unsigned int* __restrict__ cntP,
            unsigned char* __restrict__ rank8, int N, int E,
            int CHUNK, int TW, int WPS, int RS) {
    __shared__ unsigned s_cnt[WPSMAX];
    int c = blockIdx.x / RS;
    int s = blockIdx.x % RS;
    int wlo = s * WPS;
    int whi = min(wlo + WPS, TW);
    int nw = whi - wlo;
    int rlo = wlo * 4, rhi = whi * 4;
    for (int i = threadIdx.x; i < nw; i += 1024) s_cnt[i] = 0;
    __syncthreads();

    int e0 = c * CHUNK;
    int e1 = min(e0 + CHUNK, E);
#define HPROC(EE, RR) do { \
        int _r = (RR); \
        if (_r >= rlo && _r < rhi) { \
            int lr = _r - rlo; \
            unsigned old = atomicAdd(&s_cnt[lr >> 2], 1u << ((lr & 3) * 8)); \
            rank8[EE] = (unsigned char)((old >> ((lr & 3) * 8)) & 255u); \
        } } while (0)
    if (e0 < e1) {
        int nv = (e1 - e0) >> 2;                 // CHUNK is 16B-aligned (mult of 4)
        const int4* ei4 = (const int4*)(ei + e0);
        for (int i = threadIdx.x; i < nv; i += 1024) {
            int4 r4 = ei4[i];
            int eb = e0 + 4 * i;
            HPROC(eb + 0, r4.x);
            HPROC(eb + 1, r4.y);
            HPROC(eb + 2, r4.z);
            HPROC(eb + 3, r4.w);
        }
        for (int e = e0 + 4 * nv + (int)threadIdx.x; e < e1; e += 1024)
            HPROC(e, ei[e]);
    }
#undef HPROC
    __syncthreads();
    for (int i = threadIdx.x; i < nw; i += 1024)
        cntP[(size_t)c * TW + wlo + i] = s_cnt[i];
}

// scan stage 1: per-256-row block sums of the row totals (16 chunks, packed bytes)
__global__ void k_scan1(const unsigned int* __restrict__ cntP, int* __restrict__ bsums,
                        int N, int TW) {
    __shared__ int sd[256];
    int i = blockIdx.x * 256 + threadIdx.x;
    int v = 0;
    if (i < N) {
        int wi = i >> 2, sh = (i & 3) * 8;
#pragma unroll
        for (int p = 0; p < PCHUNK; p++)
            v += (int)((cntP[(size_t)p * TW + wi] >> sh) & 255u);
    }
    sd[threadIdx.x] = v;
    __syncthreads();
    for (int off = 128; off > 0; off >>= 1) {
        if (threadIdx.x < off) sd[threadIdx.x] += sd[threadIdx.x + off];
        __syncthreads();
    }
    if (threadIdx.x == 0) bsums[blockIdx.x] = sd[0];
}

// scan stage 2+3 fused.
__global__ void k_scan23(const unsigned int* __restrict__ cntP, const int* __restrict__ bsums,
                         int* __restrict__ row_ptr, int* __restrict__ base,
                         int N, int nb, int TW) {
    __shared__ int sd[256];
    __shared__ int ex[512];
    int t = threadIdx.x;
    int a0 = (2 * t     < nb) ? bsums[2 * t]     : 0;
    int a1 = (2 * t + 1 < nb) ? bsums[2 * t + 1] : 0;
    sd[t] = a0 + a1;
    __syncthreads();
    for (int off = 1; off < 256; off <<= 1) {
        int v = (t >= off) ? sd[t - off] : 0;
        __syncthreads();
        sd[t] += v;
        __syncthreads();
    }
    int pairExcl = (t == 0) ? 0 : sd[t - 1];
    ex[2 * t] = pairExcl;
    ex[2 * t + 1] = pairExcl + a0;
    __syncthreads();
    int myBase = ex[blockIdx.x];
    __syncthreads();

    int i = blockIdx.x * 256 + t;
    int c[PCHUNK];
    int v = 0;
    if (i < N) {
        int wi = i >> 2, sh = (i & 3) * 8;
#pragma unroll
        for (int p = 0; p < PCHUNK; p++) {
            c[p] = (int)((cntP[(size_t)p * TW + wi] >> sh) & 255u);
            v += c[p];
        }
    }
    sd[t] = v;
    __syncthreads();
    for (int off = 1; off < 256; off <<= 1) {
        int u = (t >= off) ? sd[t - off] : 0;
        __syncthreads();
        sd[t] += u;
        __syncthreads();
    }
    int excl = sd[t] - v + myBase;
    if (i < N) {
        row_ptr[i] = excl;
        int run = excl;
#pragma unroll
        for (int p = 0; p < PCHUNK; p++) { base[(size_t)p * N + i] = run; run += c[p]; }
        if (i == N - 1) row_ptr[N] = excl + v;
    }
}

// Thread-per-edge, no atomics: pos = base[p][row] + rank8[e], p = e/CHUNK via
// exact magic-multiply. Pre-decodes the filter scalar for ALL 3 layers
// (lerp from 3 LUTs staged in LDS) and writes one 16B record per edge:
// {col, fv_l0, fv_l1, fv_l2} (fp16 bits). k_layer then needs zero decode.
__global__ __launch_bounds__(256)
void k_scatter(const int* __restrict__ ei, const float* __restrict__ dist,
               const unsigned char* __restrict__ rank8, const int* __restrict__ base,
               const float* __restrict__ lut, u32x4* __restrict__ recs4,
               int N, int E, unsigned long long M) {
    __shared__ float sl[NLAYERS * (LUTN + 1)];   // 24588 B
#pragma unroll
    for (int l = 0; l < NLAYERS; l++)
        for (int i = threadIdx.x; i <= LUTN; i += 256)
            sl[l * (LUTN + 1) + i] = lut[l * LUTSTRIDE + i];
    __syncthreads();

    for (int e = blockIdx.x * 256 + threadIdx.x; e < E; e += gridDim.x * 256) {
        unsigned p = (unsigned)(((unsigned long long)(unsigned)e * M) >> 38);
        int row = ei[e], col = ei[E + e];
        float d = dist[e];
        float td = d * ((float)LUTN / CUTOFF);
        int i0 = (int)td;
        i0 = max(0, min(i0, LUTN - 1));
        float fr = td - (float)i0;
        union { _Float16 h; unsigned short s; } cv0, cv1, cv2;
        {
            float f = sl[i0];
            cv0.h = (_Float16)(f + fr * (sl[i0 + 1] - f));
        }
        {
            float f = sl[(LUTN + 1) + i0];
            cv1.h = (_Float16)(f + fr * (sl[(LUTN + 1) + i0 + 1] - f));
        }
        {
            float f = sl[2 * (LUTN + 1) + i0];
            cv2.h = (_Float16)(f + fr * (sl[2 * (LUTN + 1) + i0 + 1] - f));
        }
        int pos = base[(size_t)p * N + row] + (int)rank8[e];
        u32x4 rec;
        rec.x = (unsigned)col;
        rec.y = (unsigned)cv0.s;
        rec.z = (unsigned)cv1.s;
        rec.w = (unsigned)cv2.s;
        __builtin_nontemporal_store(rec, &recs4[pos]);
    }
}

// Fused layer. Phase A: group-owns-row — 8 groups x 8 lanes; each group walks
// ONE row with a 4-edge unroll (4 independent rec->gather chains in flight),
// lane ci accumulating its own 16B slot of h[col]. No cross-lane reduce, no
// per-row lockstep, no decode (fv pre-lerped at scatter). Two passes cover the
// wave's 16 rows. Phase B: 64x64x2 MLP as 16 MFMAs (fp16, BN folded in W2').
// Barrier-free (wave-private LDS rows).
__global__ __launch_bounds__(256, 8)
void k_layer(const int* __restrict__ row_ptr, const u32x4* __restrict__ recs4,
             const h8* __restrict__ Wsw, const float* __restrict__ b1,
             const float* __restrict__ b2p, const _Float16* __restrict__ h_in,
             _Float16* __restrict__ h_out, int N, int l) {
    __shared__ _Float16 sA[64 * ASTRIDE];   // 9216 B

    int lane = threadIdx.x & 63;
    int w = threadIdx.x >> 6;
    int base = blockIdx.x * 64 + w * 16;    // this wave's 16 nodes
    int g = lane >> 3, ci = lane & 7;       // 8 groups x 8 lanes
    const uint4* h4 = (const uint4*)h_in;   // 8 halves per uint4; 8 per row

    // ---- phase A ----
#pragma unroll
    for (int half = 0; half < 2; half++) {
        int node = base + half * 8 + g;     // group g owns this row
        h2 acc[4];
#pragma unroll
        for (int q = 0; q < 4; q++) acc[q] = (h2){(_Float16)0.f, (_Float16)0.f};
        if (node < N) {
            int s = row_ptr[node], t = row_ptr[node + 1];
            for (int k = s; k < t; k += 4) {
                int k1 = (k + 1 < t) ? k + 1 : k;
                int k2 = (k + 2 < t) ? k + 2 : k;
                int k3 = (k + 3 < t) ? k + 3 : k;
                u32x4 r0 = recs4[k];
                u32x4 r1 = recs4[k1];
                u32x4 r2 = recs4[k2];
                u32x4 r3 = recs4[k3];
                unsigned f0 = (l == 0) ? r0.y : ((l == 1) ? r0.z : r0.w);
                unsigned f1 = (l == 0) ? r1.y : ((l == 1) ? r1.z : r1.w);
                unsigned f2 = (l == 0) ? r2.y : ((l == 1) ? r2.z : r2.w);
                unsigned f3 = (l == 0) ? r3.y : ((l == 1) ? r3.z : r3.w);
                f1 = (k + 1 < t) ? f1 : 0u;
                f2 = (k + 2 < t) ? f2 : 0u;
                f3 = (k + 3 < t) ? f3 : 0u;
                union { uint4 u; h2 v[4]; } p0, p1, p2, p3;
                p0.u = h4[r0.x * 8u + (unsigned)ci];
                p1.u = h4[r1.x * 8u + (unsigned)ci];
                p2.u = h4[r2.x * 8u + (unsigned)ci];
                p3.u = h4[r3.x * 8u + (unsigned)ci];
                union { unsigned u; h2 v; } a0, a1, a2, a3;
                a0.u = f0 | (f0 << 16);
                a1.u = f1 | (f1 << 16);
                a2.u = f2 | (f2 << 16);
                a3.u = f3 | (f3 << 16);
#pragma unroll
                for (int q = 0; q < 4; q++) acc[q] += a0.v * p0.v[q];
#pragma unroll
                for (int q = 0; q < 4; q++) acc[q] += a1.v * p1.v[q];
#pragma unroll
                for (int q = 0; q < 4; q++) acc[q] += a2.v * p2.v[q];
#pragma unroll
                for (int q = 0; q < 4; q++) acc[q] += a3.v * p3.v[q];
            }
        }
        union { uint4 u4; h2 v[4]; } pk;
#pragma unroll
        for (int q = 0; q < 4; q++) pk.v[q] = acc[q];
        *(uint4*)&sA[(size_t)(w * 16 + half * 8 + g) * ASTRIDE + ci * 8] = pk.u4;
    }
    // wave-private LDS rows: in-wave ds ordering, no barrier needed

    // ---- phase B: MFMA MLP ----
    int q4 = lane >> 4, c16 = lane & 15;
    int rowb = w * 16;
    const h8* WB1 = Wsw;            // frags [kt][nt][lane]
    const h8* WB2 = Wsw + 8 * 64;
    h8 A0 = *(const h8*)&sA[(size_t)(rowb + c16) * ASTRIDE + q4 * 8];
    h8 A1 = *(const h8*)&sA[(size_t)(rowb + c16) * ASTRIDE + 32 + q4 * 8];
    f32x4 C1[4];
#pragma unroll
    for (int nt = 0; nt < 4; nt++) {
        f32x4 c = {0.f, 0.f, 0.f, 0.f};
        c = __builtin_amdgcn_mfma_f32_16x16x32_f16(A0, WB1[nt * 64 + lane], c, 0, 0, 0);
        c = __builtin_amdgcn_mfma_f32_16x16x32_f16(A1, WB1[(4 + nt) * 64 + lane], c, 0, 0, 0);
        C1[nt] = c;
    }
#pragma unroll
    for (int nt = 0; nt < 4; nt++) {
        float bb = b1[nt * 16 + c16];
#pragma unroll
        for (int reg = 0; reg < 4; reg++) {
            float v = softplus_f(C1[nt][reg] + bb);
            sA[(size_t)(rowb + q4 * 4 + reg) * ASTRIDE + nt * 16 + c16] = (_Float16)v;
        }
    }
    h8 M0 = *(const h8*)&sA[(size_t)(rowb + c16) * ASTRIDE + q4 * 8];
    h8 M1 = *(const h8*)&sA[(size_t)(rowb + c16) * ASTRIDE + 32 + q4 * 8];
    f32x4 C2[4];
#pragma unroll
    for (int nt = 0; nt < 4; nt++) {
        f32x4 c = {0.f, 0.f, 0.f, 0.f};
        c = __builtin_amdgcn_mfma_f32_16x16x32_f16(M0, WB2[nt * 64 + lane], c, 0, 0, 0);
        c = __builtin_amdgcn_mfma_f32_16x16x32_f16(M1, WB2[(4 + nt) * 64 + lane], c, 0, 0, 0);
        C2[nt] = c;
    }
    // epilogue: + b2' (BN folded), fp16 residual, dbuf write
#pragma unroll
    for (int nt = 0; nt < 4; nt++) {
        float bb2 = b2p[nt * 16 + c16];
#pragma unroll
        for (int reg = 0; reg < 4; reg++) {
            int node = base + q4 * 4 + reg;
            if (node < N) {
                size_t idx = (size_t)node * H + nt * 16 + c16;
                float hn = (float)h_in[idx] + C2[nt][reg] + bb2;
                h_out[idx] = (_Float16)hn;
            }
        }
    }
}

// Stage 1 of mean: per-block partial sums to DISTINCT rows — no atomics.
__global__ __launch_bounds__(256)
void k_mean(const _Float16* __restrict__ hb, float* __restrict__ partials, int N) {
    __shared__ float s_r[4][H];
    int lane = threadIdx.x & 63;
    int w = threadIdx.x >> 6;
    int wg = blockIdx.x * 4 + w;
    int stride = gridDim.x * 4;
    float local = 0.f;
    for (int i = wg; i < N; i += stride) local += (float)hb[(size_t)i * H + lane];
    s_r[w][lane] = local;
    __syncthreads();
    if (w == 0) {
        float s = s_r[0][lane] + s_r[1][lane] + s_r[2][lane] + s_r[3][lane];
        partials[(size_t)blockIdx.x * H + lane] = s;
    }
}

// Stage 2: one block reduces MEANB partial rows, then the tiny output MLP.
__global__ __launch_bounds__(256)
void k_final(const float* __restrict__ partials, int N,
             const float* __restrict__ oW1, const float* __restrict__ ob1,
             const float* __restrict__ og1, const float* __restrict__ obt1,
             const float* __restrict__ oW2, const float* __restrict__ ob2,
             const float* __restrict__ og2, const float* __restrict__ obt2,
             const float* __restrict__ fin_W, const float* __restrict__ fin_b,
             float* __restrict__ out) {
    __shared__ float red[4][H];
    __shared__ float sg[H], su[H / 2], sv[H / 2];
    int t = threadIdx.x;
    int ch = t & 63, grp = t >> 6;
    float s = 0.f;
    for (int b = grp; b < MEANB; b += 4) s += partials[(size_t)b * H + ch];
    red[grp][ch] = s;
    __syncthreads();
    if (t < H) sg[t] = (red[0][t] + red[1][t] + red[2][t] + red[3][t]) / (float)N;
    __syncthreads();
    int j = t;
    if (j < H / 2) {
        float acc = ob1[j];
        for (int k = 0; k < H; k++) acc += sg[k] * oW1[k * (H / 2) + j];
        su[j] = softplus_f(acc) * BN_INV * og1[j] + obt1[j];
    }
    __syncthreads();
    if (j < H / 2) {
        float acc = ob2[j];
        for (int k = 0; k < H / 2; k++) acc += su[k] * oW2[k * (H / 2) + j];
        sv[j] = softplus_f(acc) * BN_INV * og2[j] + obt2[j];
    }
    __syncthreads();
    if (j < 3) {
        float acc = fin_b[j];
        for (int k = 0; k < H / 2; k++) acc += sv[k] * fin_W[k * 3 + j];
        out[j] = acc;
    }
}

extern "C" void kernel_launch(void* const* d_in, const int* in_sizes, int n_in,
                              void* d_out, int out_size, void* d_ws, size_t ws_size,
                              hipStream_t stream) {
    const float* x      = (const float*)d_in[0];
    const int*   ei     = (const int*)d_in[1];
    const float* dist   = (const float*)d_in[2];
    /* d_in[3] edge_attr: unused by reference */
    const float* emb_W  = (const float*)d_in[4];
    const float* emb_b  = (const float*)d_in[5];
    const float* fW1    = (const float*)d_in[6];
    const float* fb1    = (const float*)d_in[7];
    const float* fW2    = (const float*)d_in[8];
    const float* fb2    = (const float*)d_in[9];
    const float* iW1    = (const float*)d_in[10];
    const float* ib1    = (const float*)d_in[11];
    const float* iW2    = (const float*)d_in[12];
    const float* ib2    = (const float*)d_in[13];
    const float* bn_g   = (const float*)d_in[14];
    const float* bn_b   = (const float*)d_in[15];
    const float* oW1    = (const float*)d_in[16];
    const float* ob1    = (const float*)d_in[17];
    const float* og1    = (const float*)d_in[18];
    const float* obt1   = (const float*)d_in[19];
    const float* oW2    = (const float*)d_in[20];
    const float* ob2    = (const float*)d_in[21];
    const float* og2    = (const float*)d_in[22];
    const float* obt2   = (const float*)d_in[23];
    const float* fin_W  = (const float*)d_in[24];
    const float* fin_b  = (const float*)d_in[25];
    float* out = (float*)d_out;

    int N = in_sizes[0] / FIN;
    int E = in_sizes[2];
    int nb_scan = (N + 255) / 256;
    int nb_edge = (E + 255) / 256;

    // histogram geometry
    int TW = (N + 3) / 4;                      // packed words over all rows
    int RS = (TW + WPSMAX - 1) / WPSMAX;       // row splits per chunk (8 @ N=100k)
    int WPS = (TW + RS - 1) / RS;              // words per split (<= WPSMAX)
    int CHUNK = (((E + PCHUNK - 1) / PCHUNK) + 3) & ~3;   // 16B-aligned edge chunk
    unsigned long long M =
        (((unsigned long long)1 << 38) + (unsigned long long)CHUNK - 1) /
        (unsigned long long)CHUNK;             // exact magic for e/CHUNK (E*CHUNK < 2^38)

    // workspace layout (16B-aligned chunks first)
    float*  ws   = (float*)d_ws;
    _Float16* h0 = (_Float16*)ws;                          // N*H fp16
    _Float16* h1 = h0 + (size_t)N * H;                     // N*H fp16
    u32x4*  recs4 = (u32x4*)(h1 + (size_t)N * H);          // E u32x4 (16B/edge)
    h8*     Wsw  = (h8*)(recs4 + E);                       // 3*2*8*64 h8
    float*  lut  = (float*)(Wsw + NLAYERS * 2 * 8 * 64);   // 3*LUTSTRIDE
    float*  partials = lut + 3 * LUTSTRIDE;                // MEANB*H
    float*  b2p  = partials + MEANB * H;                   // L*H
    unsigned int* cntP = (unsigned int*)(b2p + NLAYERS * H);     // PCHUNK*TW
    int*    basep = (int*)(cntP + (size_t)PCHUNK * TW);    // PCHUNK*N
    int*    row_ptr = basep + (size_t)PCHUNK * N;          // N+1
    int*    bsums   = row_ptr + (N + 1);                   // nb_scan (<=512)
    unsigned char* rank8 = (unsigned char*)(bsums + 512);  // E bytes

    int nbE = (N + 3) / 4;
    int nb_setup = nbE + NLAYERS * LUTB + 12;
    k_setup<<<nb_setup, 256, 0, stream>>>(x, emb_W, emb_b, h0,
                                          fW1, fb1, fW2, fb2, iW1, iW2,
                                          bn_g, bn_b, ib2, Wsw, b2p, lut, N);

    k_hist<<<PCHUNK * RS, 1024, 0, stream>>>(ei, cntP, rank8, N, E, CHUNK, TW, WPS, RS);
    k_scan1<<<nb_scan, 256, 0, stream>>>(cntP, bsums, N, TW);
    k_scan23<<<nb_scan, 256, 0, stream>>>(cntP, bsums, row_ptr, basep, N, nb_scan, TW);

    int nb_scat = nb_edge < 2048 ? nb_edge : 2048;
    k_scatter<<<nb_scat, 256, 0, stream>>>(ei, dist, rank8, basep, lut, recs4, N, E, M);

    _Float16* hp[2] = {h0, h1};
    int nb_tile = (N + 63) / 64;
    for (int l = 0; l < NLAYERS; l++) {
        k_layer<<<nb_tile, 256, 0, stream>>>(row_ptr, recs4,
                                             Wsw + (size_t)l * 1024,
                                             ib1 + l * H, b2p + l * H,
                                             hp[l & 1], hp[(l + 1) & 1], N, l);
    }
    _Float16* h_final = hp[NLAYERS & 1];

    k_mean<<<MEANB, 256, 0, stream>>>(h_final, partials, N);
    k_final<<<1, 256, 0, stream>>>(partials, N, oW1, ob1, og1, obt1,
                                   oW2, ob2, og2, obt2, fin_W, fin_b, out);
}

// Round 4
// 376.843 us; speedup vs baseline: 1.0864x; 1.0864x over previous
//
#include <hip/hip_runtime.h>
#include <hip/hip_fp16.h>
#include <math.h>

#define CUTOFF 5.0f
#define H 64
#define FIN 16
#define NLAYERS 3
#define LUTN 2048          // intervals; table has LUTN+1 entries
#define LUTSTRIDE 2052     // padded per-layer stride
#define ASTRIDE 72         // LDS row stride in halves (144B, 16B-aligned)
#define PCHUNK 16          // edge chunks == scatter base partitions
#define WPSMAX 3136        // max packed words per row-split (12.5KB LDS)
#define MEANB 256          // blocks in mean pass (partials rows)
#define LUTB 9             // lut blocks per layer (9*256 >= 2049)

// 1/sqrt(1 + 1e-3)  (BN inference, moving mean 0 / var 1)
#define BN_INV 0.999500374750f

typedef _Float16 h8 __attribute__((ext_vector_type(8)));
typedef _Float16 h2 __attribute__((ext_vector_type(2)));
typedef float f32x4 __attribute__((ext_vector_type(4)));

__device__ __forceinline__ float softplus_f(float x) {
    return fmaxf(x, 0.f) + __logf(1.f + __expf(-fabsf(x)));
}

// ---- K1: mega setup. Block roles by blockIdx range:
//   [0, nbE)                 embed 4 nodes/block -> h0 fp16
//   [nbE, nbE+27)            LUT: inline wsum/bsum in LDS, 256 entries/block
//   [nbE+27, nbE+39)         weight swizzle Wsw + b2p
__global__ __launch_bounds__(256)
void k_setup(const float* __restrict__ x, const float* __restrict__ emb_W,
             const float* __restrict__ emb_b, _Float16* __restrict__ h0,
             const float* __restrict__ fW1, const float* __restrict__ fb1,
             const float* __restrict__ fW2, const float* __restrict__ fb2,
             const float* __restrict__ iW1, const float* __restrict__ iW2,
             const float* __restrict__ bn_g, const float* __restrict__ bn_b,
             const float* __restrict__ ib2, h8* __restrict__ Wsw,
             float* __restrict__ b2p, float* __restrict__ lut, int N) {
    __shared__ float swsum[64];
    __shared__ float sbsum;
    int b = blockIdx.x;
    int t = threadIdx.x;
    int nbE = (N + 3) / 4;
    if (b < nbE) {
        int lane = t & 63;
        int w = t >> 6;
        int node = b * 4 + w;
        if (node < N) {
            float acc = emb_b[lane];
#pragma unroll
            for (int k = 0; k < FIN; k++) acc += x[node * FIN + k] * emb_W[k * H + lane];
            h0[(size_t)node * H + lane] = (_Float16)acc;
        }
    } else if (b < nbE + NLAYERS * LUTB) {
        int lb = b - nbE;
        int l = lb / LUTB, part = lb % LUTB;
        if (t < 64) {
            float s = 0.f;
            for (int j = 0; j < H; j++) s += fW2[l * H * H + t * H + j];
            swsum[t] = s;
        }
        if (t == 64) {
            float s = 0.f;
            for (int j = 0; j < H; j++) s += fb2[l * H + j];
            sbsum = s;
        }
        __syncthreads();
        int i = part * 256 + t;
        if (i <= LUTN) {
            float d = (float)i * (CUTOFF / (float)LUTN);
            float scaled = d * (2.0f / CUTOFF) - 1.0f;
            float cut = 0.5f * (__cosf(d * (3.14159265358979f / CUTOFF)) + 1.0f);
            if (d > CUTOFF) cut = 0.f;
            float s = 0.f;
            for (int hh = 0; hh < H; hh++) {
                int wi = l * H + hh;
                s += tanhf(scaled * fW1[wi] + fb1[wi]) * swsum[hh];
            }
            lut[l * LUTSTRIDE + i] = cut * (s + sbsum);
        }
    } else {
        int tid = (b - nbE - NLAYERS * LUTB) * 256 + t;
        if (tid < NLAYERS * H)
            b2p[tid] = ib2[tid] * BN_INV * bn_g[tid] + bn_b[tid];
        if (tid < NLAYERS * 2 * 8 * 64) {
            int lane = tid & 63;
            int frag = (tid >> 6) & 7;
            int mat  = (tid >> 9) & 1;
            int l    = tid >> 10;
            int kt = frag >> 2, nt = frag & 3;
            int n = nt * 16 + (lane & 15);
            int k0 = kt * 32 + (lane >> 4) * 8;
            const float* W = (mat ? iW2 : iW1) + l * H * H;
            float scale = mat ? BN_INV * bn_g[l * H + n] : 1.0f;
            h8 v;
#pragma unroll
            for (int j = 0; j < 8; j++) v[j] = (_Float16)(W[(k0 + j) * H + n] * scale);
            Wsw[tid] = v;
        }
    }
}

// LDS histogram + rank. Edge chunk c = e/CHUNK (16 chunks); RS row-split
// blocks per chunk, each counts rows [s*WPS*4, (s+1)*WPS*4) in packed
// byte-per-row LDS counters. atomicAdd's returned byte == within-(chunk,row)
// rank. No global atomics, no global zeroing.
__global__ __launch_bounds__(1024)
void k_hist(const int* __restrict__ ei, unsigned int* __restrict__ cntP,
            unsigned char* __restrict__ rank8, int N, int E,
            int CHUNK, int TW, int WPS, int RS) {
    __shared__ unsigned s_cnt[WPSMAX];
    int c = blockIdx.x / RS;
    int s = blockIdx.x % RS;
    int wlo = s * WPS;
    int whi = min(wlo + WPS, TW);
    int nw = whi - wlo;
    int rlo = wlo * 4, rhi = whi * 4;
    for (int i = threadIdx.x; i < nw; i += 1024) s_cnt[i] = 0;
    __syncthreads();

    int e0 = c * CHUNK;
    int e1 = min(e0 + CHUNK, E);
#define HPROC(EE, RR) do { \
        int _r = (RR); \
        if (_r >= rlo && _r < rhi) { \
            int lr = _r - rlo; \
            unsigned old = atomicAdd(&s_cnt[lr >> 2], 1u << ((lr & 3) * 8)); \
            rank8[EE] = (unsigned char)((old >> ((lr & 3) * 8)) & 255u); \
        } } while (0)
    if (e0 < e1) {
        int nv = (e1 - e0) >> 2;                 // CHUNK is 16B-aligned (mult of 4)
        const int4* ei4 = (const int4*)(ei + e0);
        for (int i = threadIdx.x; i < nv; i += 1024) {
            int4 r4 = ei4[i];
            int eb = e0 + 4 * i;
            HPROC(eb + 0, r4.x);
            HPROC(eb + 1, r4.y);
            HPROC(eb + 2, r4.z);
            HPROC(eb + 3, r4.w);
        }
        for (int e = e0 + 4 * nv + (int)threadIdx.x; e < e1; e += 1024)
            HPROC(e, ei[e]);
    }
#undef HPROC
    __syncthreads();
    for (int i = threadIdx.x; i < nw; i += 1024)
        cntP[(size_t)c * TW + wlo + i] = s_cnt[i];
}

// scan stage 1: per-256-row block sums of the row totals (16 chunks, packed bytes)
__global__ void k_scan1(const unsigned int* __restrict__ cntP, int* __restrict__ bsums,
                        int N, int TW) {
    __shared__ int sd[256];
    int i = blockIdx.x * 256 + threadIdx.x;
    int v = 0;
    if (i < N) {
        int wi = i >> 2, sh = (i & 3) * 8;
#pragma unroll
        for (int p = 0; p < PCHUNK; p++)
            v += (int)((cntP[(size_t)p * TW + wi] >> sh) & 255u);
    }
    sd[threadIdx.x] = v;
    __syncthreads();
    for (int off = 128; off > 0; off >>= 1) {
        if (threadIdx.x < off) sd[threadIdx.x] += sd[threadIdx.x + off];
        __syncthreads();
    }
    if (threadIdx.x == 0) bsums[blockIdx.x] = sd[0];
}

// scan stage 2+3 fused.
__global__ void k_scan23(const unsigned int* __restrict__ cntP, const int* __restrict__ bsums,
                         int* __restrict__ row_ptr, int* __restrict__ base,
                         int N, int nb, int TW) {
    __shared__ int sd[256];
    __shared__ int ex[512];
    int t = threadIdx.x;
    int a0 = (2 * t     < nb) ? bsums[2 * t]     : 0;
    int a1 = (2 * t + 1 < nb) ? bsums[2 * t + 1] : 0;
    sd[t] = a0 + a1;
    __syncthreads();
    for (int off = 1; off < 256; off <<= 1) {
        int v = (t >= off) ? sd[t - off] : 0;
        __syncthreads();
        sd[t] += v;
        __syncthreads();
    }
    int pairExcl = (t == 0) ? 0 : sd[t - 1];
    ex[2 * t] = pairExcl;
    ex[2 * t + 1] = pairExcl + a0;
    __syncthreads();
    int myBase = ex[blockIdx.x];
    __syncthreads();

    int i = blockIdx.x * 256 + t;
    int c[PCHUNK];
    int v = 0;
    if (i < N) {
        int wi = i >> 2, sh = (i & 3) * 8;
#pragma unroll
        for (int p = 0; p < PCHUNK; p++) {
            c[p] = (int)((cntP[(size_t)p * TW + wi] >> sh) & 255u);
            v += c[p];
        }
    }
    sd[t] = v;
    __syncthreads();
    for (int off = 1; off < 256; off <<= 1) {
        int u = (t >= off) ? sd[t - off] : 0;
        __syncthreads();
        sd[t] += u;
        __syncthreads();
    }
    int excl = sd[t] - v + myBase;
    if (i < N) {
        row_ptr[i] = excl;
        int run = excl;
#pragma unroll
        for (int p = 0; p < PCHUNK; p++) { base[(size_t)p * N + i] = run; run += c[p]; }
        if (i == N - 1) row_ptr[N] = excl + v;
    }
}

// Thread-per-edge, no atomics: pos = base[p][row] + rank8[e], p = e/CHUNK via
// exact magic-multiply. Pack {col:17b | d_quant:15b}; nontemporal store
// (4B record — decode happens in k_layer where it's nearly free).
__global__ __launch_bounds__(256)
void k_scatter(const int* __restrict__ ei, const float* __restrict__ dist,
               const unsigned char* __restrict__ rank8, const int* __restrict__ base,
               unsigned int* __restrict__ recs, int N, int E, unsigned long long M) {
    int e = blockIdx.x * 256 + threadIdx.x;
    if (e >= E) return;
    unsigned p = (unsigned)(((unsigned long long)(unsigned)e * M) >> 38);
    int row = ei[e], col = ei[E + e];
    float d = dist[e];
    int didx = (int)(d * (32768.0f / CUTOFF) + 0.5f);
    didx = max(0, min(didx, 32767));
    int pos = base[(size_t)p * N + row] + (int)rank8[e];
    __builtin_nontemporal_store(((unsigned)col << 15) | (unsigned)didx, &recs[pos]);
}

// Fused layer. Phase A: group-owns-row — 8 groups x 8 lanes; each group walks
// ONE row with a 4-edge unroll (4 independent rec->gather chains in flight),
// lane ci accumulating its own 16B slot of h[col]. No cross-lane reduce, no
// per-row lockstep. fv lerped inline from LDS LUT (intra-group reads are
// same-address broadcasts). Two passes cover the wave's 16 rows.
// Phase B: 64x64x2 MLP as 16 MFMAs (fp16, BN folded in W2').
__global__ __launch_bounds__(256, 8)
void k_layer(const int* __restrict__ row_ptr, const unsigned int* __restrict__ recs,
             const float* __restrict__ lutl, const h8* __restrict__ Wsw,
             const float* __restrict__ b1, const float* __restrict__ b2p,
             const _Float16* __restrict__ h_in, _Float16* __restrict__ h_out,
             int N) {
    __shared__ float s_lut[LUTN + 1];       // 8196 B
    __shared__ _Float16 sA[64 * ASTRIDE];   // 9216 B
    for (int i = threadIdx.x; i <= LUTN; i += 256) s_lut[i] = lutl[i];
    __syncthreads();

    int lane = threadIdx.x & 63;
    int w = threadIdx.x >> 6;
    int base = blockIdx.x * 64 + w * 16;    // this wave's 16 nodes
    int g = lane >> 3, ci = lane & 7;       // 8 groups x 8 lanes
    const uint4* h4 = (const uint4*)h_in;   // 8 halves per uint4; 8 per row

    // ---- phase A ----
#pragma unroll
    for (int half = 0; half < 2; half++) {
        int node = base + half * 8 + g;     // group g owns this row
        h2 acc[4];
#pragma unroll
        for (int q = 0; q < 4; q++) acc[q] = (h2){(_Float16)0.f, (_Float16)0.f};
        if (node < N) {
            int s = row_ptr[node], t = row_ptr[node + 1];
            for (int k = s; k < t; k += 4) {
                int k1 = (k + 1 < t) ? k + 1 : k;
                int k2 = (k + 2 < t) ? k + 2 : k;
                int k3 = (k + 3 < t) ? k + 3 : k;
                unsigned r0 = recs[k];
                unsigned r1 = recs[k1];
                unsigned r2 = recs[k2];
                unsigned r3 = recs[k3];
                // decode: fv = lerp(s_lut, didx/16) — broadcast reads in-group
                float td0 = (float)(r0 & 32767u) * (1.0f / 16.0f);
                float td1 = (float)(r1 & 32767u) * (1.0f / 16.0f);
                float td2 = (float)(r2 & 32767u) * (1.0f / 16.0f);
                float td3 = (float)(r3 & 32767u) * (1.0f / 16.0f);
                int i0 = (int)td0, i1 = (int)td1, i2 = (int)td2, i3 = (int)td3;
                float fr0 = td0 - (float)i0, fr1 = td1 - (float)i1;
                float fr2 = td2 - (float)i2, fr3 = td3 - (float)i3;
                float f00 = s_lut[i0], f01 = s_lut[i1];
                float f02 = s_lut[i2], f03 = s_lut[i3];
                float fv0 = f00 + fr0 * (s_lut[i0 + 1] - f00);
                float fv1 = f01 + fr1 * (s_lut[i1 + 1] - f01);
                float fv2 = f02 + fr2 * (s_lut[i2 + 1] - f02);
                float fv3 = f03 + fr3 * (s_lut[i3 + 1] - f03);
                fv1 = (k + 1 < t) ? fv1 : 0.f;
                fv2 = (k + 2 < t) ? fv2 : 0.f;
                fv3 = (k + 3 < t) ? fv3 : 0.f;
                union { uint4 u; h2 v[4]; } p0, p1, p2, p3;
                p0.u = h4[(r0 >> 15) * 8u + (unsigned)ci];
                p1.u = h4[(r1 >> 15) * 8u + (unsigned)ci];
                p2.u = h4[(r2 >> 15) * 8u + (unsigned)ci];
                p3.u = h4[(r3 >> 15) * 8u + (unsigned)ci];
                _Float16 fh0 = (_Float16)fv0, fh1 = (_Float16)fv1;
                _Float16 fh2 = (_Float16)fv2, fh3 = (_Float16)fv3;
                h2 a0 = (h2){fh0, fh0};
                h2 a1 = (h2){fh1, fh1};
                h2 a2 = (h2){fh2, fh2};
                h2 a3 = (h2){fh3, fh3};
#pragma unroll
                for (int q = 0; q < 4; q++) acc[q] += a0 * p0.v[q];
#pragma unroll
                for (int q = 0; q < 4; q++) acc[q] += a1 * p1.v[q];
#pragma unroll
                for (int q = 0; q < 4; q++) acc[q] += a2 * p2.v[q];
#pragma unroll
                for (int q = 0; q < 4; q++) acc[q] += a3 * p3.v[q];
            }
        }
        union { uint4 u4; h2 v[4]; } pk;
#pragma unroll
        for (int q = 0; q < 4; q++) pk.v[q] = acc[q];
        *(uint4*)&sA[(size_t)(w * 16 + half * 8 + g) * ASTRIDE + ci * 8] = pk.u4;
    }
    // wave-private LDS rows: in-wave ds ordering, no barrier needed

    // ---- phase B: MFMA MLP ----
    int q4 = lane >> 4, c16 = lane & 15;
    int rowb = w * 16;
    const h8* WB1 = Wsw;            // frags [kt][nt][lane]
    const h8* WB2 = Wsw + 8 * 64;
    h8 A0 = *(const h8*)&sA[(size_t)(rowb + c16) * ASTRIDE + q4 * 8];
    h8 A1 = *(const h8*)&sA[(size_t)(rowb + c16) * ASTRIDE + 32 + q4 * 8];
    f32x4 C1[4];
#pragma unroll
    for (int nt = 0; nt < 4; nt++) {
        f32x4 c = {0.f, 0.f, 0.f, 0.f};
        c = __builtin_amdgcn_mfma_f32_16x16x32_f16(A0, WB1[nt * 64 + lane], c, 0, 0, 0);
        c = __builtin_amdgcn_mfma_f32_16x16x32_f16(A1, WB1[(4 + nt) * 64 + lane], c, 0, 0, 0);
        C1[nt] = c;
    }
#pragma unroll
    for (int nt = 0; nt < 4; nt++) {
        float bb = b1[nt * 16 + c16];
#pragma unroll
        for (int reg = 0; reg < 4; reg++) {
            float v = softplus_f(C1[nt][reg] + bb);
            sA[(size_t)(rowb + q4 * 4 + reg) * ASTRIDE + nt * 16 + c16] = (_Float16)v;
        }
    }
    h8 M0 = *(const h8*)&sA[(size_t)(rowb + c16) * ASTRIDE + q4 * 8];
    h8 M1 = *(const h8*)&sA[(size_t)(rowb + c16) * ASTRIDE + 32 + q4 * 8];
    f32x4 C2[4];
#pragma unroll
    for (int nt = 0; nt < 4; nt++) {
        f32x4 c = {0.f, 0.f, 0.f, 0.f};
        c = __builtin_amdgcn_mfma_f32_16x16x32_f16(M0, WB2[nt * 64 + lane], c, 0, 0, 0);
        c = __builtin_amdgcn_mfma_f32_16x16x32_f16(M1, WB2[(4 + nt) * 64 + lane], c, 0, 0, 0);
        C2[nt] = c;
    }
    // epilogue: + b2' (BN folded), fp16 residual, dbuf write
#pragma unroll
    for (int nt = 0; nt < 4; nt++) {
        float bb2 = b2p[nt * 16 + c16];
#pragma unroll
        for (int reg = 0; reg < 4; reg++) {
            int node = base + q4 * 4 + reg;
            if (node < N) {
                size_t idx = (size_t)node * H + nt * 16 + c16;
                float hn = (float)h_in[idx] + C2[nt][reg] + bb2;
                h_out[idx] = (_Float16)hn;
            }
        }
    }
}

// Stage 1 of mean: per-block partial sums to DISTINCT rows — no atomics.
__global__ __launch_bounds__(256)
void k_mean(const _Float16* __restrict__ hb, float* __restrict__ partials, int N) {
    __shared__ float s_r[4][H];
    int lane = threadIdx.x & 63;
    int w = threadIdx.x >> 6;
    int wg = blockIdx.x * 4 + w;
    int stride = gridDim.x * 4;
    float local = 0.f;
    for (int i = wg; i < N; i += stride) local += (float)hb[(size_t)i * H + lane];
    s_r[w][lane] = local;
    __syncthreads();
    if (w == 0) {
        float s = s_r[0][lane] + s_r[1][lane] + s_r[2][lane] + s_r[3][lane];
        partials[(size_t)blockIdx.x * H + lane] = s;
    }
}

// Stage 2: one block reduces MEANB partial rows, then the tiny output MLP.
__global__ __launch_bounds__(256)
void k_final(const float* __restrict__ partials, int N,
             const float* __restrict__ oW1, const float* __restrict__ ob1,
             const float* __restrict__ og1, const float* __restrict__ obt1,
             const float* __restrict__ oW2, const float* __restrict__ ob2,
             const float* __restrict__ og2, const float* __restrict__ obt2,
             const float* __restrict__ fin_W, const float* __restrict__ fin_b,
             float* __restrict__ out) {
    __shared__ float red[4][H];
    __shared__ float sg[H], su[H / 2], sv[H / 2];
    int t = threadIdx.x;
    int ch = t & 63, grp = t >> 6;
    float s = 0.f;
    for (int b = grp; b < MEANB; b += 4) s += partials[(size_t)b * H + ch];
    red[grp][ch] = s;
    __syncthreads();
    if (t < H) sg[t] = (red[0][t] + red[1][t] + red[2][t] + red[3][t]) / (float)N;
    __syncthreads();
    int j = t;
    if (j < H / 2) {
        float acc = ob1[j];
        for (int k = 0; k < H; k++) acc += sg[k] * oW1[k * (H / 2) + j];
        su[j] = softplus_f(acc) * BN_INV * og1[j] + obt1[j];
    }
    __syncthreads();
    if (j < H / 2) {
        float acc = ob2[j];
        for (int k = 0; k < H / 2; k++) acc += su[k] * oW2[k * (H / 2) + j];
        sv[j] = softplus_f(acc) * BN_INV * og2[j] + obt2[j];
    }
    __syncthreads();
    if (j < 3) {
        float acc = fin_b[j];
        for (int k = 0; k < H / 2; k++) acc += sv[k] * fin_W[k * 3 + j];
        out[j] = acc;
    }
}

extern "C" void kernel_launch(void* const* d_in, const int* in_sizes, int n_in,
                              void* d_out, int out_size, void* d_ws, size_t ws_size,
                              hipStream_t stream) {
    const float* x      = (const float*)d_in[0];
    const int*   ei     = (const int*)d_in[1];
    const float* dist   = (const float*)d_in[2];
    /* d_in[3] edge_attr: unused by reference */
    const float* emb_W  = (const float*)d_in[4];
    const float* emb_b  = (const float*)d_in[5];
    const float* fW1    = (const float*)d_in[6];
    const float* fb1    = (const float*)d_in[7];
    const float* fW2    = (const float*)d_in[8];
    const float* fb2    = (const float*)d_in[9];
    const float* iW1    = (const float*)d_in[10];
    const float* ib1    = (const float*)d_in[11];
    const float* iW2    = (const float*)d_in[12];
    const float* ib2    = (const float*)d_in[13];
    const float* bn_g   = (const float*)d_in[14];
    const float* bn_b   = (const float*)d_in[15];
    const float* oW1    = (const float*)d_in[16];
    const float* ob1    = (const float*)d_in[17];
    const float* og1    = (const float*)d_in[18];
    const float* obt1   = (const float*)d_in[19];
    const float* oW2    = (const float*)d_in[20];
    const float* ob2    = (const float*)d_in[21];
    const float* og2    = (const float*)d_in[22];
    const float* obt2   = (const float*)d_in[23];
    const float* fin_W  = (const float*)d_in[24];
    const float* fin_b  = (const float*)d_in[25];
    float* out = (float*)d_out;

    int N = in_sizes[0] / FIN;
    int E = in_sizes[2];
    int nb_scan = (N + 255) / 256;
    int nb_edge = (E + 255) / 256;

    // histogram geometry
    int TW = (N + 3) / 4;                      // packed words over all rows
    int RS = (TW + WPSMAX - 1) / WPSMAX;       // row splits per chunk (8 @ N=100k)
    int WPS = (TW + RS - 1) / RS;              // words per split (<= WPSMAX)
    int CHUNK = (((E + PCHUNK - 1) / PCHUNK) + 3) & ~3;   // 16B-aligned edge chunk
    unsigned long long M =
        (((unsigned long long)1 << 38) + (unsigned long long)CHUNK - 1) /
        (unsigned long long)CHUNK;             // exact magic for e/CHUNK (E*CHUNK < 2^38)

    // workspace layout (16B-aligned chunks first)
    float*  ws   = (float*)d_ws;
    _Float16* h0 = (_Float16*)ws;                          // N*H fp16
    _Float16* h1 = h0 + (size_t)N * H;                     // N*H fp16
    unsigned int* recs = (unsigned int*)(h1 + (size_t)N * H);    // E uint32
    h8*     Wsw  = (h8*)(recs + E);                        // 3*2*8*64 h8
    float*  lut  = (float*)(Wsw + NLAYERS * 2 * 8 * 64);   // 3*LUTSTRIDE
    float*  partials = lut + 3 * LUTSTRIDE;                // MEANB*H
    float*  b2p  = partials + MEANB * H;                   // L*H
    unsigned int* cntP = (unsigned int*)(b2p + NLAYERS * H);     // PCHUNK*TW
    int*    basep = (int*)(cntP + (size_t)PCHUNK * TW);    // PCHUNK*N
    int*    row_ptr = basep + (size_t)PCHUNK * N;          // N+1
    int*    bsums   = row_ptr + (N + 1);                   // nb_scan (<=512)
    unsigned char* rank8 = (unsigned char*)(bsums + 512);  // E bytes

    int nbE = (N + 3) / 4;
    int nb_setup = nbE + NLAYERS * LUTB + 12;
    k_setup<<<nb_setup, 256, 0, stream>>>(x, emb_W, emb_b, h0,
                                          fW1, fb1, fW2, fb2, iW1, iW2,
                                          bn_g, bn_b, ib2, Wsw, b2p, lut, N);

    k_hist<<<PCHUNK * RS, 1024, 0, stream>>>(ei, cntP, rank8, N, E, CHUNK, TW, WPS, RS);
    k_scan1<<<nb_scan, 256, 0, stream>>>(cntP, bsums, N, TW);
    k_scan23<<<nb_scan, 256, 0, stream>>>(cntP, bsums, row_ptr, basep, N, nb_scan, TW);

    k_scatter<<<nb_edge, 256, 0, stream>>>(ei, dist, rank8, basep, recs, N, E, M);

    _Float16* hp[2] = {h0, h1};
    int nb_tile = (N + 63) / 64;
    for (int l = 0; l < NLAYERS; l++) {
        k_layer<<<nb_tile, 256, 0, stream>>>(row_ptr, recs, lut + (size_t)l * LUTSTRIDE,
                                             Wsw + (size_t)l * 1024,
                                             ib1 + l * H, b2p + l * H,
                                             hp[l & 1], hp[(l + 1) & 1], N);
    }
    _Float16* h_final = hp[NLAYERS & 1];

    k_mean<<<MEANB, 256, 0, stream>>>(h_final, partials, N);
    k_final<<<1, 256, 0, stream>>>(partials, N, oW1, ob1, og1, obt1,
                                   oW2, ob2, og2, obt2, fin_W, fin_b, out);
}

// Round 5
// 367.534 us; speedup vs baseline: 1.1139x; 1.0253x over previous
//
#include <hip/hip_runtime.h>
#include <hip/hip_fp16.h>
#include <math.h>

#define CUTOFF 5.0f
#define H 64
#define FIN 16
#define NLAYERS 3
#define LUTN 2048          // intervals; table has LUTN+1 entries
#define LUTSTRIDE 2052     // padded per-layer stride
#define ASTRIDE 72         // LDS row stride in halves (144B, 16B-aligned)
#define PCHUNK 16          // edge chunks == scatter base partitions
#define WPSMAX 3136        // max packed words per row-split (12.5KB LDS)
#define MEANB 256          // blocks in mean pass (partials rows)
#define SUBSC 4            // scatter sub-splits per (chunk,row-split)

// 1/sqrt(1 + 1e-3)  (BN inference, moving mean 0 / var 1)
#define BN_INV 0.999500374750f

typedef _Float16 h8 __attribute__((ext_vector_type(8)));
typedef _Float16 h2 __attribute__((ext_vector_type(2)));
typedef float f32x4 __attribute__((ext_vector_type(4)));

__device__ __forceinline__ float softplus_f(float x) {
    return fmaxf(x, 0.f) + __logf(1.f + __expf(-fabsf(x)));
}

// ---- K_pre: fused setup + histogram. Block roles by blockIdx range:
//   [0, nbH)                     LDS histogram+rank (c = b%16, s = b/16 so the
//                                8 row-split siblings of chunk c share XCD c%8
//                                -> chunk edge stream read once per XCD L2)
//   [nbH, nbH+nbE16)             embed 16 nodes/block -> h0 fp16
//   [.., +9)                     LUT: inline wsum/bsum, 1024 entries/block
//   [.., +3)                     weight swizzle Wsw + b2p
__global__ __launch_bounds__(1024)
void k_pre(const float* __restrict__ x, const float* __restrict__ emb_W,
           const float* __restrict__ emb_b, _Float16* __restrict__ h0,
           const float* __restrict__ fW1, const float* __restrict__ fb1,
           const float* __restrict__ fW2, const float* __restrict__ fb2,
           const float* __restrict__ iW1, const float* __restrict__ iW2,
           const float* __restrict__ bn_g, const float* __restrict__ bn_b,
           const float* __restrict__ ib2, h8* __restrict__ Wsw,
           float* __restrict__ b2p, float* __restrict__ lut,
           const int* __restrict__ ei, unsigned int* __restrict__ cntP,
           unsigned char* __restrict__ rank8,
           int N, int E, int CHUNK, int TW, int WPS, int RS,
           int nbH, int nbE16) {
    __shared__ unsigned s_cnt[WPSMAX];
    __shared__ float swsum[64];
    __shared__ float sbsum;
    int b = blockIdx.x;
    int t = threadIdx.x;
    if (b < nbH) {
        // ---- histogram role ----
        int c = b % PCHUNK;
        int s = b / PCHUNK;
        int wlo = s * WPS;
        int whi = min(wlo + WPS, TW);
        int nw = whi - wlo;
        int rlo = wlo * 4, rhi = whi * 4;
        for (int i = t; i < nw; i += 1024) s_cnt[i] = 0;
        __syncthreads();
        int e0 = c * CHUNK;
        int e1 = min(e0 + CHUNK, E);
#define HPROC(EE, RR) do { \
        int _r = (RR); \
        if (_r >= rlo && _r < rhi) { \
            int lr = _r - rlo; \
            unsigned old = atomicAdd(&s_cnt[lr >> 2], 1u << ((lr & 3) * 8)); \
            rank8[EE] = (unsigned char)((old >> ((lr & 3) * 8)) & 255u); \
        } } while (0)
        if (e0 < e1) {
            int nv = (e1 - e0) >> 2;             // CHUNK is 16B-aligned
            const int4* ei4 = (const int4*)(ei + e0);
            for (int i = t; i < nv; i += 1024) {
                int4 r4 = ei4[i];
                int eb = e0 + 4 * i;
                HPROC(eb + 0, r4.x);
                HPROC(eb + 1, r4.y);
                HPROC(eb + 2, r4.z);
                HPROC(eb + 3, r4.w);
            }
            for (int e = e0 + 4 * nv + t; e < e1; e += 1024)
                HPROC(e, ei[e]);
        }
#undef HPROC
        __syncthreads();
        for (int i = t; i < nw; i += 1024)
            cntP[(size_t)c * TW + wlo + i] = s_cnt[i];
    } else if (b < nbH + nbE16) {
        // ---- embed role: 16 nodes/block ----
        int lane = t & 63;
        int w = t >> 6;
        int node = (b - nbH) * 16 + w;
        if (node < N) {
            float acc = emb_b[lane];
#pragma unroll
            for (int k = 0; k < FIN; k++) acc += x[node * FIN + k] * emb_W[k * H + lane];
            h0[(size_t)node * H + lane] = (_Float16)acc;
        }
    } else if (b < nbH + nbE16 + NLAYERS * 3) {
        // ---- LUT role ----
        int lb = b - nbH - nbE16;
        int l = lb / 3, part = lb % 3;
        if (t < 64) {
            float s = 0.f;
            for (int j = 0; j < H; j++) s += fW2[l * H * H + t * H + j];
            swsum[t] = s;
        }
        if (t == 64) {
            float s = 0.f;
            for (int j = 0; j < H; j++) s += fb2[l * H + j];
            sbsum = s;
        }
        __syncthreads();
        int i = part * 1024 + t;
        if (i <= LUTN) {
            float d = (float)i * (CUTOFF / (float)LUTN);
            float scaled = d * (2.0f / CUTOFF) - 1.0f;
            float cut = 0.5f * (__cosf(d * (3.14159265358979f / CUTOFF)) + 1.0f);
            if (d > CUTOFF) cut = 0.f;
            float s = 0.f;
            for (int hh = 0; hh < H; hh++) {
                int wi = l * H + hh;
                s += tanhf(scaled * fW1[wi] + fb1[wi]) * swsum[hh];
            }
            lut[l * LUTSTRIDE + i] = cut * (s + sbsum);
        }
    } else {
        // ---- weight swizzle role ----
        int tid = (b - nbH - nbE16 - NLAYERS * 3) * 1024 + t;
        if (tid < NLAYERS * H)
            b2p[tid] = ib2[tid] * BN_INV * bn_g[tid] + bn_b[tid];
        if (tid < NLAYERS * 2 * 8 * 64) {
            int lane = tid & 63;
            int frag = (tid >> 6) & 7;
            int mat  = (tid >> 9) & 1;
            int l    = tid >> 10;
            int kt = frag >> 2, nt = frag & 3;
            int n = nt * 16 + (lane & 15);
            int k0 = kt * 32 + (lane >> 4) * 8;
            const float* W = (mat ? iW2 : iW1) + l * H * H;
            float scale = mat ? BN_INV * bn_g[l * H + n] : 1.0f;
            h8 v;
#pragma unroll
            for (int j = 0; j < 8; j++) v[j] = (_Float16)(W[(k0 + j) * H + n] * scale);
            Wsw[tid] = v;
        }
    }
}

// scan stage 1: per-256-row block sums of the row totals (16 chunks, packed bytes)
__global__ void k_scan1(const unsigned int* __restrict__ cntP, int* __restrict__ bsums,
                        int N, int TW) {
    __shared__ int sd[256];
    int i = blockIdx.x * 256 + threadIdx.x;
    int v = 0;
    if (i < N) {
        int wi = i >> 2, sh = (i & 3) * 8;
#pragma unroll
        for (int p = 0; p < PCHUNK; p++)
            v += (int)((cntP[(size_t)p * TW + wi] >> sh) & 255u);
    }
    sd[threadIdx.x] = v;
    __syncthreads();
    for (int off = 128; off > 0; off >>= 1) {
        if (threadIdx.x < off) sd[threadIdx.x] += sd[threadIdx.x + off];
        __syncthreads();
    }
    if (threadIdx.x == 0) bsums[blockIdx.x] = sd[0];
}

// scan stage 2+3 fused.
__global__ void k_scan23(const unsigned int* __restrict__ cntP, const int* __restrict__ bsums,
                         int* __restrict__ row_ptr, int* __restrict__ base,
                         int N, int nb, int TW) {
    __shared__ int sd[256];
    __shared__ int ex[512];
    int t = threadIdx.x;
    int a0 = (2 * t     < nb) ? bsums[2 * t]     : 0;
    int a1 = (2 * t + 1 < nb) ? bsums[2 * t + 1] : 0;
    sd[t] = a0 + a1;
    __syncthreads();
    for (int off = 1; off < 256; off <<= 1) {
        int v = (t >= off) ? sd[t - off] : 0;
        __syncthreads();
        sd[t] += v;
        __syncthreads();
    }
    int pairExcl = (t == 0) ? 0 : sd[t - 1];
    ex[2 * t] = pairExcl;
    ex[2 * t + 1] = pairExcl + a0;
    __syncthreads();
    int myBase = ex[blockIdx.x];
    __syncthreads();

    int i = blockIdx.x * 256 + t;
    int c[PCHUNK];
    int v = 0;
    if (i < N) {
        int wi = i >> 2, sh = (i & 3) * 8;
#pragma unroll
        for (int p = 0; p < PCHUNK; p++) {
            c[p] = (int)((cntP[(size_t)p * TW + wi] >> sh) & 255u);
            v += c[p];
        }
    }
    sd[t] = v;
    __syncthreads();
    for (int off = 1; off < 256; off <<= 1) {
        int u = (t >= off) ? sd[t - off] : 0;
        __syncthreads();
        sd[t] += u;
        __syncthreads();
    }
    int excl = sd[t] - v + myBase;
    if (i < N) {
        row_ptr[i] = excl;
        int run = excl;
#pragma unroll
        for (int p = 0; p < PCHUNK; p++) { base[(size_t)p * N + i] = run; run += c[p]; }
        if (i == N - 1) row_ptr[N] = excl + v;
    }
}

// XCD-localized scatter: block b = sub*(PCHUNK*RS) + c*RS + s. With RS==8,
// XCD = b%8 = s, so ALL writer-blocks of row-split s share XCD s: their
// plain (non-NT) stores into split-s's contiguous output region combine in
// that XCD's L2 into full sectors -> writeback ~E*4B instead of E*32B.
// Partition p == c is implicit (no magic divide); base[c][rlo:rhi] is a
// 50KB L2-resident slice. Redundant chunk re-reads are L3-absorbed.
__global__ __launch_bounds__(1024)
void k_scatter2(const int* __restrict__ ei, const float* __restrict__ dist,
                const unsigned char* __restrict__ rank8, const int* __restrict__ base,
                unsigned int* __restrict__ recs, int N, int E,
                int CHUNK, int WPS, int RS) {
    int b = blockIdx.x;
    int grp = PCHUNK * RS;
    int sub = b / grp;
    int r = b % grp;
    int c = r / RS, s = r % RS;
    int rlo = s * WPS * 4;
    int rhi = min(rlo + WPS * 4, N);
    int csub = CHUNK / SUBSC;                  // 4-aligned (CHUNK 16-aligned)
    int e0 = c * CHUNK + sub * csub;
    int e1 = min(e0 + csub, E);

#define SPROC(EE, RR) do { \
        int _r = (RR); \
        if (_r >= rlo && _r < rhi) { \
            int _e = (EE); \
            int col = ei[E + _e]; \
            float d = dist[_e]; \
            int didx = (int)(d * (32768.0f / CUTOFF) + 0.5f); \
            didx = max(0, min(didx, 32767)); \
            int pos = base[(size_t)c * N + _r] + (int)rank8[_e]; \
            recs[pos] = ((unsigned)col << 15) | (unsigned)didx; \
        } } while (0)
    if (e0 < e1) {
        int nv = (e1 - e0) >> 2;
        const int4* ei4 = (const int4*)(ei + e0);
        for (int i = threadIdx.x; i < nv; i += 1024) {
            int4 r4 = ei4[i];
            int eb = e0 + 4 * i;
            SPROC(eb + 0, r4.x);
            SPROC(eb + 1, r4.y);
            SPROC(eb + 2, r4.z);
            SPROC(eb + 3, r4.w);
        }
        for (int e = e0 + 4 * nv + (int)threadIdx.x; e < e1; e += 1024)
            SPROC(e, ei[e]);
    }
#undef SPROC
}

// Fused layer. Phase A: group-owns-row — 8 groups x 8 lanes; each group walks
// ONE row with a 4-edge unroll (4 independent rec->gather chains in flight),
// lane ci accumulating its own 16B slot of h[col]. fv lerped inline from LDS
// LUT (intra-group reads are same-address broadcasts). Phase B: 64x64x2 MLP
// as 16 MFMAs (fp16, BN folded in W2').
__global__ __launch_bounds__(256, 8)
void k_layer(const int* __restrict__ row_ptr, const unsigned int* __restrict__ recs,
             const float* __restrict__ lutl, const h8* __restrict__ Wsw,
             const float* __restrict__ b1, const float* __restrict__ b2p,
             const _Float16* __restrict__ h_in, _Float16* __restrict__ h_out,
             int N) {
    __shared__ float s_lut[LUTN + 1];       // 8196 B
    __shared__ _Float16 sA[64 * ASTRIDE];   // 9216 B
    for (int i = threadIdx.x; i <= LUTN; i += 256) s_lut[i] = lutl[i];
    __syncthreads();

    int lane = threadIdx.x & 63;
    int w = threadIdx.x >> 6;
    int base = blockIdx.x * 64 + w * 16;    // this wave's 16 nodes
    int g = lane >> 3, ci = lane & 7;       // 8 groups x 8 lanes
    const uint4* h4 = (const uint4*)h_in;   // 8 halves per uint4; 8 per row

    // ---- phase A ----
#pragma unroll
    for (int half = 0; half < 2; half++) {
        int node = base + half * 8 + g;     // group g owns this row
        h2 acc[4];
#pragma unroll
        for (int q = 0; q < 4; q++) acc[q] = (h2){(_Float16)0.f, (_Float16)0.f};
        if (node < N) {
            int s = row_ptr[node], t = row_ptr[node + 1];
            for (int k = s; k < t; k += 4) {
                int k1 = (k + 1 < t) ? k + 1 : k;
                int k2 = (k + 2 < t) ? k + 2 : k;
                int k3 = (k + 3 < t) ? k + 3 : k;
                unsigned r0 = recs[k];
                unsigned r1 = recs[k1];
                unsigned r2 = recs[k2];
                unsigned r3 = recs[k3];
                // decode: fv = lerp(s_lut, didx/16) — broadcast reads in-group
                float td0 = (float)(r0 & 32767u) * (1.0f / 16.0f);
                float td1 = (float)(r1 & 32767u) * (1.0f / 16.0f);
                float td2 = (float)(r2 & 32767u) * (1.0f / 16.0f);
                float td3 = (float)(r3 & 32767u) * (1.0f / 16.0f);
                int i0 = (int)td0, i1 = (int)td1, i2 = (int)td2, i3 = (int)td3;
                float fr0 = td0 - (float)i0, fr1 = td1 - (float)i1;
                float fr2 = td2 - (float)i2, fr3 = td3 - (float)i3;
                float f00 = s_lut[i0], f01 = s_lut[i1];
                float f02 = s_lut[i2], f03 = s_lut[i3];
                float fv0 = f00 + fr0 * (s_lut[i0 + 1] - f00);
                float fv1 = f01 + fr1 * (s_lut[i1 + 1] - f01);
                float fv2 = f02 + fr2 * (s_lut[i2 + 1] - f02);
                float fv3 = f03 + fr3 * (s_lut[i3 + 1] - f03);
                fv1 = (k + 1 < t) ? fv1 : 0.f;
                fv2 = (k + 2 < t) ? fv2 : 0.f;
                fv3 = (k + 3 < t) ? fv3 : 0.f;
                union { uint4 u; h2 v[4]; } p0, p1, p2, p3;
                p0.u = h4[(r0 >> 15) * 8u + (unsigned)ci];
                p1.u = h4[(r1 >> 15) * 8u + (unsigned)ci];
                p2.u = h4[(r2 >> 15) * 8u + (unsigned)ci];
                p3.u = h4[(r3 >> 15) * 8u + (unsigned)ci];
                _Float16 fh0 = (_Float16)fv0, fh1 = (_Float16)fv1;
                _Float16 fh2 = (_Float16)fv2, fh3 = (_Float16)fv3;
                h2 a0 = (h2){fh0, fh0};
                h2 a1 = (h2){fh1, fh1};
                h2 a2 = (h2){fh2, fh2};
                h2 a3 = (h2){fh3, fh3};
#pragma unroll
                for (int q = 0; q < 4; q++) acc[q] += a0 * p0.v[q];
#pragma unroll
                for (int q = 0; q < 4; q++) acc[q] += a1 * p1.v[q];
#pragma unroll
                for (int q = 0; q < 4; q++) acc[q] += a2 * p2.v[q];
#pragma unroll
                for (int q = 0; q < 4; q++) acc[q] += a3 * p3.v[q];
            }
        }
        union { uint4 u4; h2 v[4]; } pk;
#pragma unroll
        for (int q = 0; q < 4; q++) pk.v[q] = acc[q];
        *(uint4*)&sA[(size_t)(w * 16 + half * 8 + g) * ASTRIDE + ci * 8] = pk.u4;
    }
    // wave-private LDS rows: in-wave ds ordering, no barrier needed

    // ---- phase B: MFMA MLP ----
    int q4 = lane >> 4, c16 = lane & 15;
    int rowb = w * 16;
    const h8* WB1 = Wsw;            // frags [kt][nt][lane]
    const h8* WB2 = Wsw + 8 * 64;
    h8 A0 = *(const h8*)&sA[(size_t)(rowb + c16) * ASTRIDE + q4 * 8];
    h8 A1 = *(const h8*)&sA[(size_t)(rowb + c16) * ASTRIDE + 32 + q4 * 8];
    f32x4 C1[4];
#pragma unroll
    for (int nt = 0; nt < 4; nt++) {
        f32x4 c = {0.f, 0.f, 0.f, 0.f};
        c = __builtin_amdgcn_mfma_f32_16x16x32_f16(A0, WB1[nt * 64 + lane], c, 0, 0, 0);
        c = __builtin_amdgcn_mfma_f32_16x16x32_f16(A1, WB1[(4 + nt) * 64 + lane], c, 0, 0, 0);
        C1[nt] = c;
    }
#pragma unroll
    for (int nt = 0; nt < 4; nt++) {
        float bb = b1[nt * 16 + c16];
#pragma unroll
        for (int reg = 0; reg < 4; reg++) {
            float v = softplus_f(C1[nt][reg] + bb);
            sA[(size_t)(rowb + q4 * 4 + reg) * ASTRIDE + nt * 16 + c16] = (_Float16)v;
        }
    }
    h8 M0 = *(const h8*)&sA[(size_t)(rowb + c16) * ASTRIDE + q4 * 8];
    h8 M1 = *(const h8*)&sA[(size_t)(rowb + c16) * ASTRIDE + 32 + q4 * 8];
    f32x4 C2[4];
#pragma unroll
    for (int nt = 0; nt < 4; nt++) {
        f32x4 c = {0.f, 0.f, 0.f, 0.f};
        c = __builtin_amdgcn_mfma_f32_16x16x32_f16(M0, WB2[nt * 64 + lane], c, 0, 0, 0);
        c = __builtin_amdgcn_mfma_f32_16x16x32_f16(M1, WB2[(4 + nt) * 64 + lane], c, 0, 0, 0);
        C2[nt] = c;
    }
    // epilogue: + b2' (BN folded), fp16 residual, dbuf write
#pragma unroll
    for (int nt = 0; nt < 4; nt++) {
        float bb2 = b2p[nt * 16 + c16];
#pragma unroll
        for (int reg = 0; reg < 4; reg++) {
            int node = base + q4 * 4 + reg;
            if (node < N) {
                size_t idx = (size_t)node * H + nt * 16 + c16;
                float hn = (float)h_in[idx] + C2[nt][reg] + bb2;
                h_out[idx] = (_Float16)hn;
            }
        }
    }
}

// Stage 1 of mean: per-block partial sums to DISTINCT rows — no atomics.
__global__ __launch_bounds__(256)
void k_mean(const _Float16* __restrict__ hb, float* __restrict__ partials, int N) {
    __shared__ float s_r[4][H];
    int lane = threadIdx.x & 63;
    int w = threadIdx.x >> 6;
    int wg = blockIdx.x * 4 + w;
    int stride = gridDim.x * 4;
    float local = 0.f;
    for (int i = wg; i < N; i += stride) local += (float)hb[(size_t)i * H + lane];
    s_r[w][lane] = local;
    __syncthreads();
    if (w == 0) {
        float s = s_r[0][lane] + s_r[1][lane] + s_r[2][lane] + s_r[3][lane];
        partials[(size_t)blockIdx.x * H + lane] = s;
    }
}

// Stage 2: one block reduces MEANB partial rows, then the tiny output MLP.
__global__ __launch_bounds__(256)
void k_final(const float* __restrict__ partials, int N,
             const float* __restrict__ oW1, const float* __restrict__ ob1,
             const float* __restrict__ og1, const float* __restrict__ obt1,
             const float* __restrict__ oW2, const float* __restrict__ ob2,
             const float* __restrict__ og2, const float* __restrict__ obt2,
             const float* __restrict__ fin_W, const float* __restrict__ fin_b,
             float* __restrict__ out) {
    __shared__ float red[4][H];
    __shared__ float sg[H], su[H / 2], sv[H / 2];
    int t = threadIdx.x;
    int ch = t & 63, grp = t >> 6;
    float s = 0.f;
    for (int b = grp; b < MEANB; b += 4) s += partials[(size_t)b * H + ch];
    red[grp][ch] = s;
    __syncthreads();
    if (t < H) sg[t] = (red[0][t] + red[1][t] + red[2][t] + red[3][t]) / (float)N;
    __syncthreads();
    int j = t;
    if (j < H / 2) {
        float acc = ob1[j];
        for (int k = 0; k < H; k++) acc += sg[k] * oW1[k * (H / 2) + j];
        su[j] = softplus_f(acc) * BN_INV * og1[j] + obt1[j];
    }
    __syncthreads();
    if (j < H / 2) {
        float acc = ob2[j];
        for (int k = 0; k < H / 2; k++) acc += su[k] * oW2[k * (H / 2) + j];
        sv[j] = softplus_f(acc) * BN_INV * og2[j] + obt2[j];
    }
    __syncthreads();
    if (j < 3) {
        float acc = fin_b[j];
        for (int k = 0; k < H / 2; k++) acc += sv[k] * fin_W[k * 3 + j];
        out[j] = acc;
    }
}

extern "C" void kernel_launch(void* const* d_in, const int* in_sizes, int n_in,
                              void* d_out, int out_size, void* d_ws, size_t ws_size,
                              hipStream_t stream) {
    const float* x      = (const float*)d_in[0];
    const int*   ei     = (const int*)d_in[1];
    const float* dist   = (const float*)d_in[2];
    /* d_in[3] edge_attr: unused by reference */
    const float* emb_W  = (const float*)d_in[4];
    const float* emb_b  = (const float*)d_in[5];
    const float* fW1    = (const float*)d_in[6];
    const float* fb1    = (const float*)d_in[7];
    const float* fW2    = (const float*)d_in[8];
    const float* fb2    = (const float*)d_in[9];
    const float* iW1    = (const float*)d_in[10];
    const float* ib1    = (const float*)d_in[11];
    const float* iW2    = (const float*)d_in[12];
    const float* ib2    = (const float*)d_in[13];
    const float* bn_g   = (const float*)d_in[14];
    const float* bn_b   = (const float*)d_in[15];
    const float* oW1    = (const float*)d_in[16];
    const float* ob1    = (const float*)d_in[17];
    const float* og1    = (const float*)d_in[18];
    const float* obt1   = (const float*)d_in[19];
    const float* oW2    = (const float*)d_in[20];
    const float* ob2    = (const float*)d_in[21];
    const float* og2    = (const float*)d_in[22];
    const float* obt2   = (const float*)d_in[23];
    const float* fin_W  = (const float*)d_in[24];
    const float* fin_b  = (const float*)d_in[25];
    float* out = (float*)d_out;

    int N = in_sizes[0] / FIN;
    int E = in_sizes[2];
    int nb_scan = (N + 255) / 256;

    // histogram / scatter geometry
    int TW = (N + 3) / 4;                      // packed words over all rows
    int RS = (TW + WPSMAX - 1) / WPSMAX;       // row splits per chunk (8 @ N=100k)
    int WPS = (TW + RS - 1) / RS;              // words per split (<= WPSMAX)
    int CHUNK = (((E + PCHUNK - 1) / PCHUNK) + 15) & ~15;  // 16-aligned edge chunk

    // workspace layout (16B-aligned chunks first)
    float*  ws   = (float*)d_ws;
    _Float16* h0 = (_Float16*)ws;                          // N*H fp16
    _Float16* h1 = h0 + (size_t)N * H;                     // N*H fp16
    unsigned int* recs = (unsigned int*)(h1 + (size_t)N * H);    // E uint32
    h8*     Wsw  = (h8*)(recs + E);                        // 3*2*8*64 h8
    float*  lut  = (float*)(Wsw + NLAYERS * 2 * 8 * 64);   // 3*LUTSTRIDE
    float*  partials = lut + 3 * LUTSTRIDE;                // MEANB*H
    float*  b2p  = partials + MEANB * H;                   // L*H
    unsigned int* cntP = (unsigned int*)(b2p + NLAYERS * H);     // PCHUNK*TW
    int*    basep = (int*)(cntP + (size_t)PCHUNK * TW);    // PCHUNK*N
    int*    row_ptr = basep + (size_t)PCHUNK * N;          // N+1
    int*    bsums   = row_ptr + (N + 1);                   // nb_scan (<=512)
    unsigned char* rank8 = (unsigned char*)(bsums + 512);  // E bytes

    int nbH = PCHUNK * RS;                     // 128 hist blocks (first -> XCD c%8)
    int nbE16 = (N + 15) / 16;
    int nb_pre = nbH + nbE16 + NLAYERS * 3 + 3;
    k_pre<<<nb_pre, 1024, 0, stream>>>(x, emb_W, emb_b, h0,
                                       fW1, fb1, fW2, fb2, iW1, iW2,
                                       bn_g, bn_b, ib2, Wsw, b2p, lut,
                                       ei, cntP, rank8,
                                       N, E, CHUNK, TW, WPS, RS, nbH, nbE16);

    k_scan1<<<nb_scan, 256, 0, stream>>>(cntP, bsums, N, TW);
    k_scan23<<<nb_scan, 256, 0, stream>>>(cntP, bsums, row_ptr, basep, N, nb_scan, TW);

    k_scatter2<<<SUBSC * PCHUNK * RS, 1024, 0, stream>>>(ei, dist, rank8, basep,
                                                         recs, N, E, CHUNK, WPS, RS);

    _Float16* hp[2] = {h0, h1};
    int nb_tile = (N + 63) / 64;
    for (int l = 0; l < NLAYERS; l++) {
        k_layer<<<nb_tile, 256, 0, stream>>>(row_ptr, recs, lut + (size_t)l * LUTSTRIDE,
                                             Wsw + (size_t)l * 1024,
                                             ib1 + l * H, b2p + l * H,
                                             hp[l & 1], hp[(l + 1) & 1], N);
    }
    _Float16* h_final = hp[NLAYERS & 1];

    k_mean<<<MEANB, 256, 0, stream>>>(h_final, partials, N);
    k_final<<<1, 256, 0, stream>>>(partials, N, oW1, ob1, og1, obt1,
                                   oW2, ob2, og2, obt2, fin_W, fin_b, out);
}

// Round 8
// 348.047 us; speedup vs baseline: 1.1763x; 1.0560x over previous
//
#include <hip/hip_runtime.h>
#include <hip/hip_fp16.h>
#include <math.h>

#define CUTOFF 5.0f
#define H 64
#define FIN 16
#define NLAYERS 3
#define LUTN 2048          // intervals; table has LUTN+1 entries
#define LUTSTRIDE 2052     // padded per-layer stride
#define ASTRIDE 72         // LDS row stride in halves (144B, 16B-aligned)
#define PCHUNK 16          // edge chunks in count pass
#define WPSMAX 3136        // max packed words per row-split (12.5KB LDS)
#define MEANB 256          // blocks in mean pass (partials rows)
#define BROWS 512          // rows per sort bucket
#define NBMAX 256          // max buckets (N <= 128K)
#define MAXC 10240         // max records per bucket LDS-sorted (40KB)
#define ABLK 4096          // edges per pass-A block

// 1/sqrt(1 + 1e-3)  (BN inference, moving mean 0 / var 1)
#define BN_INV 0.999500374750f

typedef _Float16 h8 __attribute__((ext_vector_type(8)));
typedef _Float16 h2 __attribute__((ext_vector_type(2)));
typedef float f32x4 __attribute__((ext_vector_type(4)));
typedef unsigned int u32x2 __attribute__((ext_vector_type(2)));

__device__ __forceinline__ float softplus_f(float x) {
    return fmaxf(x, 0.f) + __logf(1.f + __expf(-fabsf(x)));
}

// ---- K_pre: fused setup + histogram. Block roles by blockIdx range:
//   [0, nbH)                 LDS histogram (counts only; c = b%16, s = b/16 so
//                            the 8 row-split siblings of chunk c share an XCD)
//   [nbH, nbH+nbE16)         embed 16 nodes/block -> h0 fp16
//   [.., +9)                 LUT: inline wsum/bsum, 1024 entries/block
//   [.., +3)                 weight swizzle Wsw + b2p
__global__ __launch_bounds__(1024)
void k_pre(const float* __restrict__ x, const float* __restrict__ emb_W,
           const float* __restrict__ emb_b, _Float16* __restrict__ h0,
           const float* __restrict__ fW1, const float* __restrict__ fb1,
           const float* __restrict__ fW2, const float* __restrict__ fb2,
           const float* __restrict__ iW1, const float* __restrict__ iW2,
           const float* __restrict__ bn_g, const float* __restrict__ bn_b,
           const float* __restrict__ ib2, h8* __restrict__ Wsw,
           float* __restrict__ b2p, float* __restrict__ lut,
           const int* __restrict__ ei, unsigned int* __restrict__ cntP,
           int N, int E, int CHUNK, int TW, int WPS, int RS,
           int nbH, int nbE16) {
    __shared__ unsigned s_cnt[WPSMAX];
    __shared__ float swsum[64];
    __shared__ float sbsum;
    int b = blockIdx.x;
    int t = threadIdx.x;
    if (b < nbH) {
        // ---- histogram role (counts only) ----
        int c = b % PCHUNK;
        int s = b / PCHUNK;
        int wlo = s * WPS;
        int whi = min(wlo + WPS, TW);
        int nw = whi - wlo;
        int rlo = wlo * 4, rhi = whi * 4;
        for (int i = t; i < nw; i += 1024) s_cnt[i] = 0;
        __syncthreads();
        int e0 = c * CHUNK;
        int e1 = min(e0 + CHUNK, E);
#define HPROC(RR) do { \
        int _r = (RR); \
        if (_r >= rlo && _r < rhi) { \
            int lr = _r - rlo; \
            atomicAdd(&s_cnt[lr >> 2], 1u << ((lr & 3) * 8)); \
        } } while (0)
        if (e0 < e1) {
            int nv = (e1 - e0) >> 2;             // CHUNK is 16-aligned
            const int4* ei4 = (const int4*)(ei + e0);
            for (int i = t; i < nv; i += 1024) {
                int4 r4 = ei4[i];
                HPROC(r4.x);
                HPROC(r4.y);
                HPROC(r4.z);
                HPROC(r4.w);
            }
            for (int e = e0 + 4 * nv + t; e < e1; e += 1024)
                HPROC(ei[e]);
        }
#undef HPROC
        __syncthreads();
        for (int i = t; i < nw; i += 1024)
            cntP[(size_t)c * TW + wlo + i] = s_cnt[i];
    } else if (b < nbH + nbE16) {
        // ---- embed role: 16 nodes/block ----
        int lane = t & 63;
        int w = t >> 6;
        int node = (b - nbH) * 16 + w;
        if (node < N) {
            float acc = emb_b[lane];
#pragma unroll
            for (int k = 0; k < FIN; k++) acc += x[node * FIN + k] * emb_W[k * H + lane];
            h0[(size_t)node * H + lane] = (_Float16)acc;
        }
    } else if (b < nbH + nbE16 + NLAYERS * 3) {
        // ---- LUT role ----
        int lb = b - nbH - nbE16;
        int l = lb / 3, part = lb % 3;
        if (t < 64) {
            float s = 0.f;
            for (int j = 0; j < H; j++) s += fW2[l * H * H + t * H + j];
            swsum[t] = s;
        }
        if (t == 64) {
            float s = 0.f;
            for (int j = 0; j < H; j++) s += fb2[l * H + j];
            sbsum = s;
        }
        __syncthreads();
        int i = part * 1024 + t;
        if (i <= LUTN) {
            float d = (float)i * (CUTOFF / (float)LUTN);
            float scaled = d * (2.0f / CUTOFF) - 1.0f;
            float cut = 0.5f * (__cosf(d * (3.14159265358979f / CUTOFF)) + 1.0f);
            if (d > CUTOFF) cut = 0.f;
            float s = 0.f;
            for (int hh = 0; hh < H; hh++) {
                int wi = l * H + hh;
                s += tanhf(scaled * fW1[wi] + fb1[wi]) * swsum[hh];
            }
            lut[l * LUTSTRIDE + i] = cut * (s + sbsum);
        }
    } else {
        // ---- weight swizzle role ----
        int tid = (b - nbH - nbE16 - NLAYERS * 3) * 1024 + t;
        if (tid < NLAYERS * H)
            b2p[tid] = ib2[tid] * BN_INV * bn_g[tid] + bn_b[tid];
        if (tid < NLAYERS * 2 * 8 * 64) {
            int lane = tid & 63;
            int frag = (tid >> 6) & 7;
            int mat  = (tid >> 9) & 1;
            int l    = tid >> 10;
            int kt = frag >> 2, nt = frag & 3;
            int n = nt * 16 + (lane & 15);
            int k0 = kt * 32 + (lane >> 4) * 8;
            const float* W = (mat ? iW2 : iW1) + l * H * H;
            float scale = mat ? BN_INV * bn_g[l * H + n] : 1.0f;
            h8 v;
#pragma unroll
            for (int j = 0; j < 8; j++) v[j] = (_Float16)(W[(k0 + j) * H + n] * scale);
            Wsw[tid] = v;
        }
    }
}

// scan stage 1: per-256-row block sums of the row totals (16 chunks, packed bytes)
__global__ void k_scan1(const unsigned int* __restrict__ cntP, int* __restrict__ bsums,
                        int N, int TW) {
    __shared__ int sd[256];
    int i = blockIdx.x * 256 + threadIdx.x;
    int v = 0;
    if (i < N) {
        int wi = i >> 2, sh = (i & 3) * 8;
#pragma unroll
        for (int p = 0; p < PCHUNK; p++)
            v += (int)((cntP[(size_t)p * TW + wi] >> sh) & 255u);
    }
    sd[threadIdx.x] = v;
    __syncthreads();
    for (int off = 128; off > 0; off >>= 1) {
        if (threadIdx.x < off) sd[threadIdx.x] += sd[threadIdx.x + off];
        __syncthreads();
    }
    if (threadIdx.x == 0) bsums[blockIdx.x] = sd[0];
}

// scan stage 2+3 fused: row_ptr + bucket cursor seed (cursor[b] = row_ptr[b*512]).
__global__ void k_scan23(const unsigned int* __restrict__ cntP, const int* __restrict__ bsums,
                         int* __restrict__ row_ptr, unsigned int* __restrict__ cursor,
                         int N, int nb, int TW) {
    __shared__ int sd[256];
    __shared__ int ex[512];
    int t = threadIdx.x;
    int a0 = (2 * t     < nb) ? bsums[2 * t]     : 0;
    int a1 = (2 * t + 1 < nb) ? bsums[2 * t + 1] : 0;
    sd[t] = a0 + a1;
    __syncthreads();
    for (int off = 1; off < 256; off <<= 1) {
        int v = (t >= off) ? sd[t - off] : 0;
        __syncthreads();
        sd[t] += v;
        __syncthreads();
    }
    int pairExcl = (t == 0) ? 0 : sd[t - 1];
    ex[2 * t] = pairExcl;
    ex[2 * t + 1] = pairExcl + a0;
    __syncthreads();
    int myBase = ex[blockIdx.x];
    __syncthreads();

    int i = blockIdx.x * 256 + t;
    int v = 0;
    if (i < N) {
        int wi = i >> 2, sh = (i & 3) * 8;
#pragma unroll
        for (int p = 0; p < PCHUNK; p++)
            v += (int)((cntP[(size_t)p * TW + wi] >> sh) & 255u);
    }
    sd[t] = v;
    __syncthreads();
    for (int off = 1; off < 256; off <<= 1) {
        int u = (t >= off) ? sd[t - off] : 0;
        __syncthreads();
        sd[t] += u;
        __syncthreads();
    }
    int excl = sd[t] - v + myBase;
    if (i < N) {
        row_ptr[i] = excl;
        if ((i & (BROWS - 1)) == 0) cursor[i / BROWS] = (unsigned)excl;
        if (i == N - 1) row_ptr[N] = excl + v;
    }
}

// Pass A: bucket scatter. Tile of ABLK edges/block; LDS-count per 512-row
// bucket; one global atomicAdd per (block,bucket) reserves space; write 8B
// staging records {col<<15|didx, row} grouped by bucket -> ~21-record
// contiguous runs (near-full sectors). All reads coalesced.
__global__ __launch_bounds__(1024)
void k_passA(const int* __restrict__ ei, const float* __restrict__ dist,
             unsigned int* __restrict__ cursor, u32x2* __restrict__ stg,
             int N, int E, int NB) {
    __shared__ unsigned s_cnt[NBMAX];
    __shared__ unsigned s_base[NBMAX];
    int t = threadIdx.x;
    int e0 = blockIdx.x * ABLK;
    for (int i = t; i < NB; i += 1024) s_cnt[i] = 0;
    __syncthreads();
    int rowv[4];
    unsigned rkv[4] = {0u, 0u, 0u, 0u};
    int bkv[4] = {0, 0, 0, 0};
#pragma unroll
    for (int j = 0; j < 4; j++) {
        int e = e0 + j * 1024 + t;
        rowv[j] = -1;
        if (e < E) {
            int r = ei[e];
            int bk = r / BROWS;
            rkv[j] = atomicAdd(&s_cnt[bk], 1u);
            bkv[j] = bk;
            rowv[j] = r;
        }
    }
    __syncthreads();
    for (int i = t; i < NB; i += 1024)
        s_base[i] = s_cnt[i] ? atomicAdd(&cursor[i], s_cnt[i]) : 0u;
    __syncthreads();
#pragma unroll
    for (int j = 0; j < 4; j++) {
        int e = e0 + j * 1024 + t;
        if (e < E) {
            int col = ei[E + e];
            float d = dist[e];
            int didx = (int)(d * (32768.0f / CUTOFF) + 0.5f);
            didx = max(0, min(didx, 32767));
            u32x2 rec;
            rec.x = ((unsigned)col << 15) | (unsigned)didx;
            rec.y = (unsigned)rowv[j];
            stg[s_base[bkv[j]] + rkv[j]] = rec;
        }
    }
}

// Pass B: per-bucket counting sort. Bucket read coalesced; per-row LDS
// cursors seeded straight from row_ptr; LDS scatter; final write coalesced.
__global__ __launch_bounds__(1024)
void k_passB(const u32x2* __restrict__ stg, const int* __restrict__ row_ptr,
             unsigned int* __restrict__ recs, int N) {
    __shared__ int s_ptr[BROWS];
    __shared__ unsigned s_out[MAXC];
    int b = blockIdx.x, t = threadIdx.x;
    int r0 = b * BROWS;
    int r1 = min(r0 + BROWS, N);
    int p0 = row_ptr[r0];
    int p1 = row_ptr[r1];
    int cnt = p1 - p0;
    for (int i = t; i < r1 - r0; i += 1024) s_ptr[i] = row_ptr[r0 + i] - p0;
    __syncthreads();
    if (cnt <= MAXC) {
        for (int i = t; i < cnt; i += 1024) {
            u32x2 rec = stg[p0 + i];
            int slot = atomicAdd(&s_ptr[(int)rec.y - r0], 1);
            s_out[slot] = rec.x;
        }
        __syncthreads();
        for (int i = t; i < cnt; i += 1024) recs[p0 + i] = s_out[i];
    } else {
        // overflow fallback (statistically never at E/N=16): global scatter
        for (int i = t; i < cnt; i += 1024) {
            u32x2 rec = stg[p0 + i];
            int slot = atomicAdd(&s_ptr[(int)rec.y - r0], 1);
            recs[p0 + slot] = rec.x;
        }
    }
}

// Fused layer. Phase A: group-owns-row — 8 groups x 8 lanes; each group walks
// ONE row with a 4-edge unroll (4 independent rec->gather chains in flight),
// lane ci accumulating its own 16B slot of h[col]. fv lerped inline from LDS
// LUT (intra-group reads are same-address broadcasts). Phase B: 64x64x2 MLP
// as 16 MFMAs (fp16, BN folded in W2').
__global__ __launch_bounds__(256, 8)
void k_layer(const int* __restrict__ row_ptr, const unsigned int* __restrict__ recs,
             const float* __restrict__ lutl, const h8* __restrict__ Wsw,
             const float* __restrict__ b1, const float* __restrict__ b2p,
             const _Float16* __restrict__ h_in, _Float16* __restrict__ h_out,
             int N) {
    __shared__ float s_lut[LUTN + 1];       // 8196 B
    __shared__ _Float16 sA[64 * ASTRIDE];   // 9216 B
    for (int i = threadIdx.x; i <= LUTN; i += 256) s_lut[i] = lutl[i];
    __syncthreads();

    int lane = threadIdx.x & 63;
    int w = threadIdx.x >> 6;
    int base = blockIdx.x * 64 + w * 16;    // this wave's 16 nodes
    int g = lane >> 3, ci = lane & 7;       // 8 groups x 8 lanes
    const uint4* h4 = (const uint4*)h_in;   // 8 halves per uint4; 8 per row

    // ---- phase A ----
#pragma unroll
    for (int half = 0; half < 2; half++) {
        int node = base + half * 8 + g;     // group g owns this row
        h2 acc[4];
#pragma unroll
        for (int q = 0; q < 4; q++) acc[q] = (h2){(_Float16)0.f, (_Float16)0.f};
        if (node < N) {
            int s = row_ptr[node], t = row_ptr[node + 1];
            for (int k = s; k < t; k += 4) {
                int k1 = (k + 1 < t) ? k + 1 : k;
                int k2 = (k + 2 < t) ? k + 2 : k;
                int k3 = (k + 3 < t) ? k + 3 : k;
                unsigned r0 = recs[k];
                unsigned r1 = recs[k1];
                unsigned r2 = recs[k2];
                unsigned r3 = recs[k3];
                // decode: fv = lerp(s_lut, didx/16) — broadcast reads in-group
                float td0 = (float)(r0 & 32767u) * (1.0f / 16.0f);
                float td1 = (float)(r1 & 32767u) * (1.0f / 16.0f);
                float td2 = (float)(r2 & 32767u) * (1.0f / 16.0f);
                float td3 = (float)(r3 & 32767u) * (1.0f / 16.0f);
                int i0 = (int)td0, i1 = (int)td1, i2 = (int)td2, i3 = (int)td3;
                float fr0 = td0 - (float)i0, fr1 = td1 - (float)i1;
                float fr2 = td2 - (float)i2, fr3 = td3 - (float)i3;
                float f00 = s_lut[i0], f01 = s_lut[i1];
                float f02 = s_lut[i2], f03 = s_lut[i3];
                float fv0 = f00 + fr0 * (s_lut[i0 + 1] - f00);
                float fv1 = f01 + fr1 * (s_lut[i1 + 1] - f01);
                float fv2 = f02 + fr2 * (s_lut[i2 + 1] - f02);
                float fv3 = f03 + fr3 * (s_lut[i3 + 1] - f03);
                fv1 = (k + 1 < t) ? fv1 : 0.f;
                fv2 = (k + 2 < t) ? fv2 : 0.f;
                fv3 = (k + 3 < t) ? fv3 : 0.f;
                union { uint4 u; h2 v[4]; } p0, p1, p2, p3;
                p0.u = h4[(r0 >> 15) * 8u + (unsigned)ci];
                p1.u = h4[(r1 >> 15) * 8u + (unsigned)ci];
                p2.u = h4[(r2 >> 15) * 8u + (unsigned)ci];
                p3.u = h4[(r3 >> 15) * 8u + (unsigned)ci];
                _Float16 fh0 = (_Float16)fv0, fh1 = (_Float16)fv1;
                _Float16 fh2 = (_Float16)fv2, fh3 = (_Float16)fv3;
                h2 a0 = (h2){fh0, fh0};
                h2 a1 = (h2){fh1, fh1};
                h2 a2 = (h2){fh2, fh2};
                h2 a3 = (h2){fh3, fh3};
#pragma unroll
                for (int q = 0; q < 4; q++) acc[q] += a0 * p0.v[q];
#pragma unroll
                for (int q = 0; q < 4; q++) acc[q] += a1 * p1.v[q];
#pragma unroll
                for (int q = 0; q < 4; q++) acc[q] += a2 * p2.v[q];
#pragma unroll
                for (int q = 0; q < 4; q++) acc[q] += a3 * p3.v[q];
            }
        }
        union { uint4 u4; h2 v[4]; } pk;
#pragma unroll
        for (int q = 0; q < 4; q++) pk.v[q] = acc[q];
        *(uint4*)&sA[(size_t)(w * 16 + half * 8 + g) * ASTRIDE + ci * 8] = pk.u4;
    }
    // wave-private LDS rows: in-wave ds ordering, no barrier needed

    // ---- phase B: MFMA MLP ----
    int q4 = lane >> 4, c16 = lane & 15;
    int rowb = w * 16;
    const h8* WB1 = Wsw;            // frags [kt][nt][lane]
    const h8* WB2 = Wsw + 8 * 64;
    h8 A0 = *(const h8*)&sA[(size_t)(rowb + c16) * ASTRIDE + q4 * 8];
    h8 A1 = *(const h8*)&sA[(size_t)(rowb + c16) * ASTRIDE + 32 + q4 * 8];
    f32x4 C1[4];
#pragma unroll
    for (int nt = 0; nt < 4; nt++) {
        f32x4 c = {0.f, 0.f, 0.f, 0.f};
        c = __builtin_amdgcn_mfma_f32_16x16x32_f16(A0, WB1[nt * 64 + lane], c, 0, 0, 0);
        c = __builtin_amdgcn_mfma_f32_16x16x32_f16(A1, WB1[(4 + nt) * 64 + lane], c, 0, 0, 0);
        C1[nt] = c;
    }
#pragma unroll
    for (int nt = 0; nt < 4; nt++) {
        float bb = b1[nt * 16 + c16];
#pragma unroll
        for (int reg = 0; reg < 4; reg++) {
            float v = softplus_f(C1[nt][reg] + bb);
            sA[(size_t)(rowb + q4 * 4 + reg) * ASTRIDE + nt * 16 + c16] = (_Float16)v;
        }
    }
    h8 M0 = *(const h8*)&sA[(size_t)(rowb + c16) * ASTRIDE + q4 * 8];
    h8 M1 = *(const h8*)&sA[(size_t)(rowb + c16) * ASTRIDE + 32 + q4 * 8];
    f32x4 C2[4];
#pragma unroll
    for (int nt = 0; nt < 4; nt++) {
        f32x4 c = {0.f, 0.f, 0.f, 0.f};
        c = __builtin_amdgcn_mfma_f32_16x16x32_f16(M0, WB2[nt * 64 + lane], c, 0, 0, 0);
        c = __builtin_amdgcn_mfma_f32_16x16x32_f16(M1, WB2[(4 + nt) * 64 + lane], c, 0, 0, 0);
        C2[nt] = c;
    }
    // epilogue: + b2' (BN folded), fp16 residual, dbuf write
#pragma unroll
    for (int nt = 0; nt < 4; nt++) {
        float bb2 = b2p[nt * 16 + c16];
#pragma unroll
        for (int reg = 0; reg < 4; reg++) {
            int node = base + q4 * 4 + reg;
            if (node < N) {
                size_t idx = (size_t)node * H + nt * 16 + c16;
                float hn = (float)h_in[idx] + C2[nt][reg] + bb2;
                h_out[idx] = (_Float16)hn;
            }
        }
    }
}

// Stage 1 of mean: per-block partial sums to DISTINCT rows — no atomics.
__global__ __launch_bounds__(256)
void k_mean(const _Float16* __restrict__ hb, float* __restrict__ partials, int N) {
    __shared__ float s_r[4][H];
    int lane = threadIdx.x & 63;
    int w = threadIdx.x >> 6;
    int wg = blockIdx.x * 4 + w;
    int stride = gridDim.x * 4;
    float local = 0.f;
    for (int i = wg; i < N; i += stride) local += (float)hb[(size_t)i * H + lane];
    s_r[w][lane] = local;
    __syncthreads();
    if (w == 0) {
        float s = s_r[0][lane] + s_r[1][lane] + s_r[2][lane] + s_r[3][lane];
        partials[(size_t)blockIdx.x * H + lane] = s;
    }
}

// Stage 2: one block reduces MEANB partial rows, then the tiny output MLP.
__global__ __launch_bounds__(256)
void k_final(const float* __restrict__ partials, int N,
             const float* __restrict__ oW1, const float* __restrict__ ob1,
             const float* __restrict__ og1, const float* __restrict__ obt1,
             const float* __restrict__ oW2, const float* __restrict__ ob2,
             const float* __restrict__ og2, const float* __restrict__ obt2,
             const float* __restrict__ fin_W, const float* __restrict__ fin_b,
             float* __restrict__ out) {
    __shared__ float red[4][H];
    __shared__ float sg[H], su[H / 2], sv[H / 2];
    int t = threadIdx.x;
    int ch = t & 63, grp = t >> 6;
    float s = 0.f;
    for (int b = grp; b < MEANB; b += 4) s += partials[(size_t)b * H + ch];
    red[grp][ch] = s;
    __syncthreads();
    if (t < H) sg[t] = (red[0][t] + red[1][t] + red[2][t] + red[3][t]) / (float)N;
    __syncthreads();
    int j = t;
    if (j < H / 2) {
        float acc = ob1[j];
        for (int k = 0; k < H; k++) acc += sg[k] * oW1[k * (H / 2) + j];
        su[j] = softplus_f(acc) * BN_INV * og1[j] + obt1[j];
    }
    __syncthreads();
    if (j < H / 2) {
        float acc = ob2[j];
        for (int k = 0; k < H / 2; k++) acc += su[k] * oW2[k * (H / 2) + j];
        sv[j] = softplus_f(acc) * BN_INV * og2[j] + obt2[j];
    }
    __syncthreads();
    if (j < 3) {
        float acc = fin_b[j];
        for (int k = 0; k < H / 2; k++) acc += sv[k] * fin_W[k * 3 + j];
        out[j] = acc;
    }
}

extern "C" void kernel_launch(void* const* d_in, const int* in_sizes, int n_in,
                              void* d_out, int out_size, void* d_ws, size_t ws_size,
                              hipStream_t stream) {
    const float* x      = (const float*)d_in[0];
    const int*   ei     = (const int*)d_in[1];
    const float* dist   = (const float*)d_in[2];
    /* d_in[3] edge_attr: unused by reference */
    const float* emb_W  = (const float*)d_in[4];
    const float* emb_b  = (const float*)d_in[5];
    const float* fW1    = (const float*)d_in[6];
    const float* fb1    = (const float*)d_in[7];
    const float* fW2    = (const float*)d_in[8];
    const float* fb2    = (const float*)d_in[9];
    const float* iW1    = (const float*)d_in[10];
    const float* ib1    = (const float*)d_in[11];
    const float* iW2    = (const float*)d_in[12];
    const float* ib2    = (const float*)d_in[13];
    const float* bn_g   = (const float*)d_in[14];
    const float* bn_b   = (const float*)d_in[15];
    const float* oW1    = (const float*)d_in[16];
    const float* ob1    = (const float*)d_in[17];
    const float* og1    = (const float*)d_in[18];
    const float* obt1   = (const float*)d_in[19];
    const float* oW2    = (const float*)d_in[20];
    const float* ob2    = (const float*)d_in[21];
    const float* og2    = (const float*)d_in[22];
    const float* obt2   = (const float*)d_in[23];
    const float* fin_W  = (const float*)d_in[24];
    const float* fin_b  = (const float*)d_in[25];
    float* out = (float*)d_out;

    int N = in_sizes[0] / FIN;
    int E = in_sizes[2];
    int nb_scan = (N + 255) / 256;

    // histogram geometry
    int TW = (N + 3) / 4;                      // packed words over all rows
    int RS = (TW + WPSMAX - 1) / WPSMAX;       // row splits per chunk (8 @ N=100k)
    int WPS = (TW + RS - 1) / RS;              // words per split (<= WPSMAX)
    int CHUNK = (((E + PCHUNK - 1) / PCHUNK) + 15) & ~15;  // 16-aligned edge chunk
    int NB = (N + BROWS - 1) / BROWS;          // sort buckets (196 @ N=100k)

    // workspace layout (16B-aligned chunks first)
    float*  ws   = (float*)d_ws;
    _Float16* h0 = (_Float16*)ws;                          // N*H fp16
    _Float16* h1 = h0 + (size_t)N * H;                     // N*H fp16
    unsigned int* recs = (unsigned int*)(h1 + (size_t)N * H);    // E uint32
    h8*     Wsw  = (h8*)(recs + E);                        // 3*2*8*64 h8
    float*  lut  = (float*)(Wsw + NLAYERS * 2 * 8 * 64);   // 3*LUTSTRIDE
    float*  partials = lut + 3 * LUTSTRIDE;                // MEANB*H
    float*  b2p  = partials + MEANB * H;                   // L*H
    u32x2*  stg  = (u32x2*)(b2p + NLAYERS * H);            // E u32x2 (8B-aligned)
    unsigned int* cntP = (unsigned int*)(stg + E);         // PCHUNK*TW
    int*    row_ptr = (int*)(cntP + (size_t)PCHUNK * TW);  // N+1
    int*    bsums   = row_ptr + (N + 1);                   // nb_scan (<=512)
    unsigned int* cursor = (unsigned int*)(bsums + 512);   // NB (<=256)

    int nbH = PCHUNK * RS;                     // 128 hist blocks
    int nbE16 = (N + 15) / 16;
    int nb_pre = nbH + nbE16 + NLAYERS * 3 + 3;
    k_pre<<<nb_pre, 1024, 0, stream>>>(x, emb_W, emb_b, h0,
                                       fW1, fb1, fW2, fb2, iW1, iW2,
                                       bn_g, bn_b, ib2, Wsw, b2p, lut,
                                       ei, cntP,
                                       N, E, CHUNK, TW, WPS, RS, nbH, nbE16);

    k_scan1<<<nb_scan, 256, 0, stream>>>(cntP, bsums, N, TW);
    k_scan23<<<nb_scan, 256, 0, stream>>>(cntP, bsums, row_ptr, cursor, N, nb_scan, TW);

    int nbA = (E + ABLK - 1) / ABLK;
    k_passA<<<nbA, 1024, 0, stream>>>(ei, dist, cursor, stg, N, E, NB);
    k_passB<<<NB, 1024, 0, stream>>>(stg, row_ptr, recs, N);

    _Float16* hp[2] = {h0, h1};
    int nb_tile = (N + 63) / 64;
    for (int l = 0; l < NLAYERS; l++) {
        k_layer<<<nb_tile, 256, 0, stream>>>(row_ptr, recs, lut + (size_t)l * LUTSTRIDE,
                                             Wsw + (size_t)l * 1024,
                                             ib1 + l * H, b2p + l * H,
                                             hp[l & 1], hp[(l + 1) & 1], N);
    }
    _Float16* h_final = hp[NLAYERS & 1];

    k_mean<<<MEANB, 256, 0, stream>>>(h_final, partials, N);
    k_final<<<1, 256, 0, stream>>>(partials, N, oW1, ob1, og1, obt1,
                                   oW2, ob2, og2, obt2, fin_W, fin_b, out);
}

// Round 9
// 339.145 us; speedup vs baseline: 1.2071x; 1.0262x over previous
//
#include <hip/hip_runtime.h>
#include <hip/hip_fp16.h>
#include <math.h>

#define CUTOFF 5.0f
#define H 64
#define FIN 16
#define NLAYERS 3
#define LUTN 2048          // intervals; table has LUTN+1 entries
#define LUTSTRIDE 2052     // padded per-layer stride
#define ASTRIDE 72         // LDS row stride in halves (144B, 16B-aligned)
#define MEANB 256          // blocks in mean pass (partials rows)
#define BROWS 512          // rows per sort bucket
#define NBMAX 256          // max buckets (N <= 128K)
#define MAXC 10240         // per-bucket stg stride AND LDS sort capacity (40KB)
#define ABLK 4096          // edges per pass-A block

// 1/sqrt(1 + 1e-3)  (BN inference, moving mean 0 / var 1)
#define BN_INV 0.999500374750f

typedef _Float16 h8 __attribute__((ext_vector_type(8)));
typedef _Float16 h2 __attribute__((ext_vector_type(2)));
typedef float f32x4 __attribute__((ext_vector_type(4)));
typedef unsigned int u32x2 __attribute__((ext_vector_type(2)));

__device__ __forceinline__ float softplus_f(float x) {
    return fmaxf(x, 0.f) + __logf(1.f + __expf(-fabsf(x)));
}

// ---- K_pre: setup only (histogram eliminated — passB self-computes row_ptr).
//   [0, nbE16)           embed 16 nodes/block -> h0 fp16
//   [.., +9)             LUT: inline wsum/bsum, 1024 entries/block
//   [.., +3)             weight swizzle Wsw + b2p + bucket cursor init
__global__ __launch_bounds__(1024)
void k_pre(const float* __restrict__ x, const float* __restrict__ emb_W,
           const float* __restrict__ emb_b, _Float16* __restrict__ h0,
           const float* __restrict__ fW1, const float* __restrict__ fb1,
           const float* __restrict__ fW2, const float* __restrict__ fb2,
           const float* __restrict__ iW1, const float* __restrict__ iW2,
           const float* __restrict__ bn_g, const float* __restrict__ bn_b,
           const float* __restrict__ ib2, h8* __restrict__ Wsw,
           float* __restrict__ b2p, float* __restrict__ lut,
           unsigned int* __restrict__ cursor, int N, int nbE16) {
    __shared__ float swsum[64];
    __shared__ float sbsum;
    int b = blockIdx.x;
    int t = threadIdx.x;
    if (b < nbE16) {
        // ---- embed role: 16 nodes/block ----
        int lane = t & 63;
        int w = t >> 6;
        int node = b * 16 + w;
        if (node < N) {
            float acc = emb_b[lane];
#pragma unroll
            for (int k = 0; k < FIN; k++) acc += x[node * FIN + k] * emb_W[k * H + lane];
            h0[(size_t)node * H + lane] = (_Float16)acc;
        }
    } else if (b < nbE16 + NLAYERS * 3) {
        // ---- LUT role ----
        int lb = b - nbE16;
        int l = lb / 3, part = lb % 3;
        if (t < 64) {
            float s = 0.f;
            for (int j = 0; j < H; j++) s += fW2[l * H * H + t * H + j];
            swsum[t] = s;
        }
        if (t == 64) {
            float s = 0.f;
            for (int j = 0; j < H; j++) s += fb2[l * H + j];
            sbsum = s;
        }
        __syncthreads();
        int i = part * 1024 + t;
        if (i <= LUTN) {
            float d = (float)i * (CUTOFF / (float)LUTN);
            float scaled = d * (2.0f / CUTOFF) - 1.0f;
            float cut = 0.5f * (__cosf(d * (3.14159265358979f / CUTOFF)) + 1.0f);
            if (d > CUTOFF) cut = 0.f;
            float s = 0.f;
            for (int hh = 0; hh < H; hh++) {
                int wi = l * H + hh;
                s += tanhf(scaled * fW1[wi] + fb1[wi]) * swsum[hh];
            }
            lut[l * LUTSTRIDE + i] = cut * (s + sbsum);
        }
    } else {
        // ---- weight swizzle role + cursor init ----
        int tid = (b - nbE16 - NLAYERS * 3) * 1024 + t;
        if (tid < NBMAX) cursor[tid] = (unsigned)tid * MAXC;
        if (tid < NLAYERS * H)
            b2p[tid] = ib2[tid] * BN_INV * bn_g[tid] + bn_b[tid];
        if (tid < NLAYERS * 2 * 8 * 64) {
            int lane = tid & 63;
            int frag = (tid >> 6) & 7;
            int mat  = (tid >> 9) & 1;
            int l    = tid >> 10;
            int kt = frag >> 2, nt = frag & 3;
            int n = nt * 16 + (lane & 15);
            int k0 = kt * 32 + (lane >> 4) * 8;
            const float* W = (mat ? iW2 : iW1) + l * H * H;
            float scale = mat ? BN_INV * bn_g[l * H + n] : 1.0f;
            h8 v;
#pragma unroll
            for (int j = 0; j < 8; j++) v[j] = (_Float16)(W[(k0 + j) * H + n] * scale);
            Wsw[tid] = v;
        }
    }
}

// Pass A: bucket scatter into fixed-stride regions. Tile of ABLK edges/block;
// LDS-count per 512-row bucket; one global atomicAdd per (block,bucket)
// reserves space in bucket b's region [b*MAXC, (b+1)*MAXC); write 8B staging
// records {col<<15|didx, row} grouped by bucket -> ~21-record contiguous
// runs (near-full sectors). All reads coalesced. cursor[b]-b*MAXC = count.
__global__ __launch_bounds__(1024)
void k_passA(const int* __restrict__ ei, const float* __restrict__ dist,
             unsigned int* __restrict__ cursor, u32x2* __restrict__ stg,
             int N, int E, int NB) {
    __shared__ unsigned s_cnt[NBMAX];
    __shared__ unsigned s_base[NBMAX];
    int t = threadIdx.x;
    int e0 = blockIdx.x * ABLK;
    for (int i = t; i < NB; i += 1024) s_cnt[i] = 0;
    __syncthreads();
    int rowv[4];
    unsigned rkv[4] = {0u, 0u, 0u, 0u};
    int bkv[4] = {0, 0, 0, 0};
#pragma unroll
    for (int j = 0; j < 4; j++) {
        int e = e0 + j * 1024 + t;
        rowv[j] = -1;
        if (e < E) {
            int r = ei[e];
            int bk = r / BROWS;
            rkv[j] = atomicAdd(&s_cnt[bk], 1u);
            bkv[j] = bk;
            rowv[j] = r;
        }
    }
    __syncthreads();
    for (int i = t; i < NB; i += 1024)
        s_base[i] = s_cnt[i] ? atomicAdd(&cursor[i], s_cnt[i]) : 0u;
    __syncthreads();
#pragma unroll
    for (int j = 0; j < 4; j++) {
        int e = e0 + j * 1024 + t;
        if (e < E) {
            int col = ei[E + e];
            float d = dist[e];
            int didx = (int)(d * (32768.0f / CUTOFF) + 0.5f);
            didx = max(0, min(didx, 32767));
            unsigned g = s_base[bkv[j]] + rkv[j];
            u32x2 rec;
            rec.x = ((unsigned)col << 15) | (unsigned)didx;
            rec.y = (unsigned)rowv[j];
            if (g < ((unsigned)bkv[j] + 1u) * MAXC)   // overflow guard (~never)
                stg[g] = rec;
        }
    }
}

// Pass B: self-contained per-bucket counting sort + row_ptr production.
// Every block redundantly scans the <=256 bucket counts (from cursor) in LDS
// to get its global base; counts its <=512 rows; 512-entry LDS scan ->
// row_ptr writes; LDS scatter; final recs write coalesced.
__global__ __launch_bounds__(1024)
void k_passB(const u32x2* __restrict__ stg, const unsigned int* __restrict__ cursor,
             int* __restrict__ row_ptr, unsigned int* __restrict__ recs,
             int N, int NB) {
    __shared__ int s_bb[NBMAX];
    __shared__ int s_c[BROWS];
    __shared__ int s_x[BROWS];
    __shared__ unsigned s_out[MAXC];
    int b = blockIdx.x, t = threadIdx.x;
    // bucket counts + redundant inclusive scan over NBMAX
    if (t < NBMAX) {
        int cb = 0;
        if (t < NB) {
            cb = (int)(cursor[t] - (unsigned)t * MAXC);
            cb = min(cb, MAXC);
        }
        s_bb[t] = cb;
    }
    __syncthreads();
    for (int off = 1; off < NBMAX; off <<= 1) {
        int v = 0;
        if (t < NBMAX && t >= off) v = s_bb[t - off];
        __syncthreads();
        if (t < NBMAX) s_bb[t] += v;
        __syncthreads();
    }
    int bbase = (b > 0) ? s_bb[b - 1] : 0;
    int cnt = s_bb[b] - bbase;
    int r0 = b * BROWS;
    int r1 = min(r0 + BROWS, N);
    int nrows = r1 - r0;
    if (t < BROWS) s_c[t] = 0;
    __syncthreads();
    const u32x2* mystg = stg + (size_t)b * MAXC;
    // count rows
    for (int i = t; i < cnt; i += 1024)
        atomicAdd(&s_c[(int)mystg[i].y - r0], 1);
    __syncthreads();
    if (t < BROWS) s_x[t] = s_c[t];
    __syncthreads();
    for (int off = 1; off < BROWS; off <<= 1) {
        int v = 0;
        if (t < BROWS && t >= off) v = s_x[t - off];
        __syncthreads();
        if (t < BROWS) s_x[t] += v;
        __syncthreads();
    }
    // exclusive offsets -> row_ptr + per-row cursors
    if (t < nrows) {
        int excl = s_x[t] - s_c[t];
        row_ptr[r0 + t] = bbase + excl;
        s_c[t] = excl;
    }
    if (b == NB - 1 && t == 0) row_ptr[N] = bbase + cnt;
    __syncthreads();
    // scatter into sorted LDS order
    for (int i = t; i < cnt; i += 1024) {
        u32x2 rec = mystg[i];
        int slot = atomicAdd(&s_c[(int)rec.y - r0], 1);
        s_out[slot] = rec.x;
    }
    __syncthreads();
    for (int i = t; i < cnt; i += 1024)
        recs[bbase + i] = s_out[i];
}

// Fused layer. Phase A: group-owns-row — 8 groups x 8 lanes; each group walks
// ONE row with a 4-edge unroll (4 independent rec->gather chains in flight),
// lane ci accumulating its own 16B slot of h[col]. fv lerped inline from LDS
// LUT (intra-group reads are same-address broadcasts). Phase B: 64x64x2 MLP
// as 16 MFMAs (fp16, BN folded in W2').
__global__ __launch_bounds__(256, 8)
void k_layer(const int* __restrict__ row_ptr, const unsigned int* __restrict__ recs,
             const float* __restrict__ lutl, const h8* __restrict__ Wsw,
             const float* __restrict__ b1, const float* __restrict__ b2p,
             const _Float16* __restrict__ h_in, _Float16* __restrict__ h_out,
             int N) {
    __shared__ float s_lut[LUTN + 1];       // 8196 B
    __shared__ _Float16 sA[64 * ASTRIDE];   // 9216 B
    for (int i = threadIdx.x; i <= LUTN; i += 256) s_lut[i] = lutl[i];
    __syncthreads();

    int lane = threadIdx.x & 63;
    int w = threadIdx.x >> 6;
    int base = blockIdx.x * 64 + w * 16;    // this wave's 16 nodes
    int g = lane >> 3, ci = lane & 7;       // 8 groups x 8 lanes
    const uint4* h4 = (const uint4*)h_in;   // 8 halves per uint4; 8 per row

    // ---- phase A ----
#pragma unroll
    for (int half = 0; half < 2; half++) {
        int node = base + half * 8 + g;     // group g owns this row
        h2 acc[4];
#pragma unroll
        for (int q = 0; q < 4; q++) acc[q] = (h2){(_Float16)0.f, (_Float16)0.f};
        if (node < N) {
            int s = row_ptr[node], t = row_ptr[node + 1];
            for (int k = s; k < t; k += 4) {
                int k1 = (k + 1 < t) ? k + 1 : k;
                int k2 = (k + 2 < t) ? k + 2 : k;
                int k3 = (k + 3 < t) ? k + 3 : k;
                unsigned r0 = recs[k];
                unsigned r1 = recs[k1];
                unsigned r2 = recs[k2];
                unsigned r3 = recs[k3];
                // decode: fv = lerp(s_lut, didx/16) — broadcast reads in-group
                float td0 = (float)(r0 & 32767u) * (1.0f / 16.0f);
                float td1 = (float)(r1 & 32767u) * (1.0f / 16.0f);
                float td2 = (float)(r2 & 32767u) * (1.0f / 16.0f);
                float td3 = (float)(r3 & 32767u) * (1.0f / 16.0f);
                int i0 = (int)td0, i1 = (int)td1, i2 = (int)td2, i3 = (int)td3;
                float fr0 = td0 - (float)i0, fr1 = td1 - (float)i1;
                float fr2 = td2 - (float)i2, fr3 = td3 - (float)i3;
                float f00 = s_lut[i0], f01 = s_lut[i1];
                float f02 = s_lut[i2], f03 = s_lut[i3];
                float fv0 = f00 + fr0 * (s_lut[i0 + 1] - f00);
                float fv1 = f01 + fr1 * (s_lut[i1 + 1] - f01);
                float fv2 = f02 + fr2 * (s_lut[i2 + 1] - f02);
                float fv3 = f03 + fr3 * (s_lut[i3 + 1] - f03);
                fv1 = (k + 1 < t) ? fv1 : 0.f;
                fv2 = (k + 2 < t) ? fv2 : 0.f;
                fv3 = (k + 3 < t) ? fv3 : 0.f;
                union { uint4 u; h2 v[4]; } p0, p1, p2, p3;
                p0.u = h4[(r0 >> 15) * 8u + (unsigned)ci];
                p1.u = h4[(r1 >> 15) * 8u + (unsigned)ci];
                p2.u = h4[(r2 >> 15) * 8u + (unsigned)ci];
                p3.u = h4[(r3 >> 15) * 8u + (unsigned)ci];
                _Float16 fh0 = (_Float16)fv0, fh1 = (_Float16)fv1;
                _Float16 fh2 = (_Float16)fv2, fh3 = (_Float16)fv3;
                h2 a0 = (h2){fh0, fh0};
                h2 a1 = (h2){fh1, fh1};
                h2 a2 = (h2){fh2, fh2};
                h2 a3 = (h2){fh3, fh3};
#pragma unroll
                for (int q = 0; q < 4; q++) acc[q] += a0 * p0.v[q];
#pragma unroll
                for (int q = 0; q < 4; q++) acc[q] += a1 * p1.v[q];
#pragma unroll
                for (int q = 0; q < 4; q++) acc[q] += a2 * p2.v[q];
#pragma unroll
                for (int q = 0; q < 4; q++) acc[q] += a3 * p3.v[q];
            }
        }
        union { uint4 u4; h2 v[4]; } pk;
#pragma unroll
        for (int q = 0; q < 4; q++) pk.v[q] = acc[q];
        *(uint4*)&sA[(size_t)(w * 16 + half * 8 + g) * ASTRIDE + ci * 8] = pk.u4;
    }
    // wave-private LDS rows: in-wave ds ordering, no barrier needed

    // ---- phase B: MFMA MLP ----
    int q4 = lane >> 4, c16 = lane & 15;
    int rowb = w * 16;
    const h8* WB1 = Wsw;            // frags [kt][nt][lane]
    const h8* WB2 = Wsw + 8 * 64;
    h8 A0 = *(const h8*)&sA[(size_t)(rowb + c16) * ASTRIDE + q4 * 8];
    h8 A1 = *(const h8*)&sA[(size_t)(rowb + c16) * ASTRIDE + 32 + q4 * 8];
    f32x4 C1[4];
#pragma unroll
    for (int nt = 0; nt < 4; nt++) {
        f32x4 c = {0.f, 0.f, 0.f, 0.f};
        c = __builtin_amdgcn_mfma_f32_16x16x32_f16(A0, WB1[nt * 64 + lane], c, 0, 0, 0);
        c = __builtin_amdgcn_mfma_f32_16x16x32_f16(A1, WB1[(4 + nt) * 64 + lane], c, 0, 0, 0);
        C1[nt] = c;
    }
#pragma unroll
    for (int nt = 0; nt < 4; nt++) {
        float bb = b1[nt * 16 + c16];
#pragma unroll
        for (int reg = 0; reg < 4; reg++) {
            float v = softplus_f(C1[nt][reg] + bb);
            sA[(size_t)(rowb + q4 * 4 + reg) * ASTRIDE + nt * 16 + c16] = (_Float16)v;
        }
    }
    h8 M0 = *(const h8*)&sA[(size_t)(rowb + c16) * ASTRIDE + q4 * 8];
    h8 M1 = *(const h8*)&sA[(size_t)(rowb + c16) * ASTRIDE + 32 + q4 * 8];
    f32x4 C2[4];
#pragma unroll
    for (int nt = 0; nt < 4; nt++) {
        f32x4 c = {0.f, 0.f, 0.f, 0.f};
        c = __builtin_amdgcn_mfma_f32_16x16x32_f16(M0, WB2[nt * 64 + lane], c, 0, 0, 0);
        c = __builtin_amdgcn_mfma_f32_16x16x32_f16(M1, WB2[(4 + nt) * 64 + lane], c, 0, 0, 0);
        C2[nt] = c;
    }
    // epilogue: + b2' (BN folded), fp16 residual, dbuf write
#pragma unroll
    for (int nt = 0; nt < 4; nt++) {
        float bb2 = b2p[nt * 16 + c16];
#pragma unroll
        for (int reg = 0; reg < 4; reg++) {
            int node = base + q4 * 4 + reg;
            if (node < N) {
                size_t idx = (size_t)node * H + nt * 16 + c16;
                float hn = (float)h_in[idx] + C2[nt][reg] + bb2;
                h_out[idx] = (_Float16)hn;
            }
        }
    }
}

// Stage 1 of mean: per-block partial sums to DISTINCT rows — no atomics.
__global__ __launch_bounds__(256)
void k_mean(const _Float16* __restrict__ hb, float* __restrict__ partials, int N) {
    __shared__ float s_r[4][H];
    int lane = threadIdx.x & 63;
    int w = threadIdx.x >> 6;
    int wg = blockIdx.x * 4 + w;
    int stride = gridDim.x * 4;
    float local = 0.f;
    for (int i = wg; i < N; i += stride) local += (float)hb[(size_t)i * H + lane];
    s_r[w][lane] = local;
    __syncthreads();
    if (w == 0) {
        float s = s_r[0][lane] + s_r[1][lane] + s_r[2][lane] + s_r[3][lane];
        partials[(size_t)blockIdx.x * H + lane] = s;
    }
}

// Stage 2: one block reduces MEANB partial rows, then the tiny output MLP.
__global__ __launch_bounds__(256)
void k_final(const float* __restrict__ partials, int N,
             const float* __restrict__ oW1, const float* __restrict__ ob1,
             const float* __restrict__ og1, const float* __restrict__ obt1,
             const float* __restrict__ oW2, const float* __restrict__ ob2,
             const float* __restrict__ og2, const float* __restrict__ obt2,
             const float* __restrict__ fin_W, const float* __restrict__ fin_b,
             float* __restrict__ out) {
    __shared__ float red[4][H];
    __shared__ float sg[H], su[H / 2], sv[H / 2];
    int t = threadIdx.x;
    int ch = t & 63, grp = t >> 6;
    float s = 0.f;
    for (int b = grp; b < MEANB; b += 4) s += partials[(size_t)b * H + ch];
    red[grp][ch] = s;
    __syncthreads();
    if (t < H) sg[t] = (red[0][t] + red[1][t] + red[2][t] + red[3][t]) / (float)N;
    __syncthreads();
    int j = t;
    if (j < H / 2) {
        float acc = ob1[j];
        for (int k = 0; k < H; k++) acc += sg[k] * oW1[k * (H / 2) + j];
        su[j] = softplus_f(acc) * BN_INV * og1[j] + obt1[j];
    }
    __syncthreads();
    if (j < H / 2) {
        float acc = ob2[j];
        for (int k = 0; k < H / 2; k++) acc += su[k] * oW2[k * (H / 2) + j];
        sv[j] = softplus_f(acc) * BN_INV * og2[j] + obt2[j];
    }
    __syncthreads();
    if (j < 3) {
        float acc = fin_b[j];
        for (int k = 0; k < H / 2; k++) acc += sv[k] * fin_W[k * 3 + j];
        out[j] = acc;
    }
}

extern "C" void kernel_launch(void* const* d_in, const int* in_sizes, int n_in,
                              void* d_out, int out_size, void* d_ws, size_t ws_size,
                              hipStream_t stream) {
    const float* x      = (const float*)d_in[0];
    const int*   ei     = (const int*)d_in[1];
    const float* dist   = (const float*)d_in[2];
    /* d_in[3] edge_attr: unused by reference */
    const float* emb_W  = (const float*)d_in[4];
    const float* emb_b  = (const float*)d_in[5];
    const float* fW1    = (const float*)d_in[6];
    const float* fb1    = (const float*)d_in[7];
    const float* fW2    = (const float*)d_in[8];
    const float* fb2    = (const float*)d_in[9];
    const float* iW1    = (const float*)d_in[10];
    const float* ib1    = (const float*)d_in[11];
    const float* iW2    = (const float*)d_in[12];
    const float* ib2    = (const float*)d_in[13];
    const float* bn_g   = (const float*)d_in[14];
    const float* bn_b   = (const float*)d_in[15];
    const float* oW1    = (const float*)d_in[16];
    const float* ob1    = (const float*)d_in[17];
    const float* og1    = (const float*)d_in[18];
    const float* obt1   = (const float*)d_in[19];
    const float* oW2    = (const float*)d_in[20];
    const float* ob2    = (const float*)d_in[21];
    const float* og2    = (const float*)d_in[22];
    const float* obt2   = (const float*)d_in[23];
    const float* fin_W  = (const float*)d_in[24];
    const float* fin_b  = (const float*)d_in[25];
    float* out = (float*)d_out;

    int N = in_sizes[0] / FIN;
    int E = in_sizes[2];
    int NB = (N + BROWS - 1) / BROWS;          // sort buckets (196 @ N=100k)

    // workspace layout (16B-aligned chunks first)
    float*  ws   = (float*)d_ws;
    _Float16* h0 = (_Float16*)ws;                          // N*H fp16
    _Float16* h1 = h0 + (size_t)N * H;                     // N*H fp16
    unsigned int* recs = (unsigned int*)(h1 + (size_t)N * H);    // E uint32
    h8*     Wsw  = (h8*)(recs + E);                        // 3*2*8*64 h8
    float*  lut  = (float*)(Wsw + NLAYERS * 2 * 8 * 64);   // 3*LUTSTRIDE
    float*  partials = lut + 3 * LUTSTRIDE;                // MEANB*H
    float*  b2p  = partials + MEANB * H;                   // L*H
    u32x2*  stg  = (u32x2*)(b2p + NLAYERS * H);            // NBMAX*MAXC u32x2
    int*    row_ptr = (int*)(stg + (size_t)NBMAX * MAXC);  // N+1
    unsigned int* cursor = (unsigned int*)(row_ptr + N + 1);     // NBMAX

    int nbE16 = (N + 15) / 16;
    int nb_pre = nbE16 + NLAYERS * 3 + 3;
    k_pre<<<nb_pre, 1024, 0, stream>>>(x, emb_W, emb_b, h0,
                                       fW1, fb1, fW2, fb2, iW1, iW2,
                                       bn_g, bn_b, ib2, Wsw, b2p, lut,
                                       cursor, N, nbE16);

    int nbA = (E + ABLK - 1) / ABLK;
    k_passA<<<nbA, 1024, 0, stream>>>(ei, dist, cursor, stg, N, E, NB);
    k_passB<<<NB, 1024, 0, stream>>>(stg, cursor, row_ptr, recs, N, NB);

    _Float16* hp[2] = {h0, h1};
    int nb_tile = (N + 63) / 64;
    for (int l = 0; l < NLAYERS; l++) {
        k_layer<<<nb_tile, 256, 0, stream>>>(row_ptr, recs, lut + (size_t)l * LUTSTRIDE,
                                             Wsw + (size_t)l * 1024,
                                             ib1 + l * H, b2p + l * H,
                                             hp[l & 1], hp[(l + 1) & 1], N);
    }
    _Float16* h_final = hp[NLAYERS & 1];

    k_mean<<<MEANB, 256, 0, stream>>>(h_final, partials, N);
    k_final<<<1, 256, 0, stream>>>(partials, N, oW1, ob1, og1, obt1,
                                   oW2, ob2, og2, obt2, fin_W, fin_b, out);
}

// Round 10
// 331.481 us; speedup vs baseline: 1.2351x; 1.0231x over previous
//
#include <hip/hip_runtime.h>
#include <hip/hip_fp16.h>
#include <math.h>

#define CUTOFF 5.0f
#define H 64
#define FIN 16
#define NLAYERS 3
#define LUTN 2048          // intervals; table has LUTN+1 entries
#define LUTSTRIDE 2052     // padded per-layer stride
#define ASTRIDE 72         // LDS row stride in halves (144B, 16B-aligned)
#define MEANB 256          // blocks in mean pass (partials rows)
#define BROWS 512          // rows per sort bucket
#define NBMAX 256          // max buckets (N <= 128K)
#define MAXC 10240         // per-bucket stg stride AND LDS sort capacity (40KB)
#define ABLK 4096          // edges per pass-A block

// 1/sqrt(1 + 1e-3)  (BN inference, moving mean 0 / var 1)
#define BN_INV 0.999500374750f

typedef _Float16 h8 __attribute__((ext_vector_type(8)));
typedef _Float16 h2 __attribute__((ext_vector_type(2)));
typedef float f32x4 __attribute__((ext_vector_type(4)));
typedef unsigned int u32x2 __attribute__((ext_vector_type(2)));

__device__ __forceinline__ float softplus_f(float x) {
    return fmaxf(x, 0.f) + __logf(1.f + __expf(-fabsf(x)));
}

// ---- K_pre: fused passA + setup. Block roles by blockIdx range:
//   [0, nbA)             passA: bucket scatter (cursor pre-zeroed by memset)
//   [nbA, +nbE16)        embed 16 nodes/block -> h0 fp16
//   [.., +9)             LUT: inline wsum/bsum, 1024 entries/block
//   [.., +3)             weight swizzle Wsw + b2p
__global__ __launch_bounds__(1024)
void k_pre(const float* __restrict__ x, const float* __restrict__ emb_W,
           const float* __restrict__ emb_b, _Float16* __restrict__ h0,
           const float* __restrict__ fW1, const float* __restrict__ fb1,
           const float* __restrict__ fW2, const float* __restrict__ fb2,
           const float* __restrict__ iW1, const float* __restrict__ iW2,
           const float* __restrict__ bn_g, const float* __restrict__ bn_b,
           const float* __restrict__ ib2, h8* __restrict__ Wsw,
           float* __restrict__ b2p, float* __restrict__ lut,
           const int* __restrict__ ei, const float* __restrict__ dist,
           unsigned int* __restrict__ cursor, u32x2* __restrict__ stg,
           int N, int E, int NB, int nbA, int nbE16) {
    __shared__ unsigned s_cnt[NBMAX];
    __shared__ unsigned s_base[NBMAX];
    __shared__ float swsum[64];
    __shared__ float sbsum;
    int b = blockIdx.x;
    int t = threadIdx.x;
    if (b < nbA) {
        // ---- passA role: bucket scatter into fixed-stride regions ----
        int e0 = b * ABLK;
        for (int i = t; i < NB; i += 1024) s_cnt[i] = 0;
        __syncthreads();
        int rowv[4];
        unsigned rkv[4] = {0u, 0u, 0u, 0u};
        int bkv[4] = {0, 0, 0, 0};
#pragma unroll
        for (int j = 0; j < 4; j++) {
            int e = e0 + j * 1024 + t;
            rowv[j] = -1;
            if (e < E) {
                int r = ei[e];
                int bk = r / BROWS;
                rkv[j] = atomicAdd(&s_cnt[bk], 1u);
                bkv[j] = bk;
                rowv[j] = r;
            }
        }
        __syncthreads();
        for (int i = t; i < NB; i += 1024)
            s_base[i] = s_cnt[i] ? atomicAdd(&cursor[i], s_cnt[i]) : 0u;
        __syncthreads();
#pragma unroll
        for (int j = 0; j < 4; j++) {
            int e = e0 + j * 1024 + t;
            if (e < E) {
                int col = ei[E + e];
                float d = dist[e];
                int didx = (int)(d * (32768.0f / CUTOFF) + 0.5f);
                didx = max(0, min(didx, 32767));
                unsigned g = s_base[bkv[j]] + rkv[j];
                u32x2 rec;
                rec.x = ((unsigned)col << 15) | (unsigned)didx;
                rec.y = (unsigned)rowv[j];
                if (g < MAXC)                      // overflow guard (~never)
                    stg[(size_t)bkv[j] * MAXC + g] = rec;
            }
        }
    } else if (b < nbA + nbE16) {
        // ---- embed role: 16 nodes/block ----
        int lane = t & 63;
        int w = t >> 6;
        int node = (b - nbA) * 16 + w;
        if (node < N) {
            float acc = emb_b[lane];
#pragma unroll
            for (int k = 0; k < FIN; k++) acc += x[node * FIN + k] * emb_W[k * H + lane];
            h0[(size_t)node * H + lane] = (_Float16)acc;
        }
    } else if (b < nbA + nbE16 + NLAYERS * 3) {
        // ---- LUT role ----
        int lb = b - nbA - nbE16;
        int l = lb / 3, part = lb % 3;
        if (t < 64) {
            float s = 0.f;
            for (int j = 0; j < H; j++) s += fW2[l * H * H + t * H + j];
            swsum[t] = s;
        }
        if (t == 64) {
            float s = 0.f;
            for (int j = 0; j < H; j++) s += fb2[l * H + j];
            sbsum = s;
        }
        __syncthreads();
        int i = part * 1024 + t;
        if (i <= LUTN) {
            float d = (float)i * (CUTOFF / (float)LUTN);
            float scaled = d * (2.0f / CUTOFF) - 1.0f;
            float cut = 0.5f * (__cosf(d * (3.14159265358979f / CUTOFF)) + 1.0f);
            if (d > CUTOFF) cut = 0.f;
            float s = 0.f;
            for (int hh = 0; hh < H; hh++) {
                int wi = l * H + hh;
                s += tanhf(scaled * fW1[wi] + fb1[wi]) * swsum[hh];
            }
            lut[l * LUTSTRIDE + i] = cut * (s + sbsum);
        }
    } else {
        // ---- weight swizzle role ----
        int tid = (b - nbA - nbE16 - NLAYERS * 3) * 1024 + t;
        if (tid < NLAYERS * H)
            b2p[tid] = ib2[tid] * BN_INV * bn_g[tid] + bn_b[tid];
        if (tid < NLAYERS * 2 * 8 * 64) {
            int lane = tid & 63;
            int frag = (tid >> 6) & 7;
            int mat  = (tid >> 9) & 1;
            int l    = tid >> 10;
            int kt = frag >> 2, nt = frag & 3;
            int n = nt * 16 + (lane & 15);
            int k0 = kt * 32 + (lane >> 4) * 8;
            const float* W = (mat ? iW2 : iW1) + l * H * H;
            float scale = mat ? BN_INV * bn_g[l * H + n] : 1.0f;
            h8 v;
#pragma unroll
            for (int j = 0; j < 8; j++) v[j] = (_Float16)(W[(k0 + j) * H + n] * scale);
            Wsw[tid] = v;
        }
    }
}

// Pass B: self-contained per-bucket counting sort + row_ptr production.
// Single stg read: each thread stages its <=10 records in registers
// (static-index unroll), counts via LDS atomics, scans, scatters from regs.
__global__ __launch_bounds__(1024)
void k_passB(const u32x2* __restrict__ stg, const unsigned int* __restrict__ cursor,
             int* __restrict__ row_ptr, unsigned int* __restrict__ recs,
             int N, int NB) {
    __shared__ int s_bb[NBMAX];
    __shared__ int s_c[BROWS];
    __shared__ int s_x[BROWS];
    __shared__ unsigned s_out[MAXC];
    int b = blockIdx.x, t = threadIdx.x;
    // bucket counts + redundant inclusive scan over NBMAX
    if (t < NBMAX) {
        int cb = 0;
        if (t < NB) cb = min((int)cursor[t], MAXC);
        s_bb[t] = cb;
    }
    __syncthreads();
    for (int off = 1; off < NBMAX; off <<= 1) {
        int v = 0;
        if (t < NBMAX && t >= off) v = s_bb[t - off];
        __syncthreads();
        if (t < NBMAX) s_bb[t] += v;
        __syncthreads();
    }
    int bbase = (b > 0) ? s_bb[b - 1] : 0;
    int cnt = s_bb[b] - bbase;
    int r0 = b * BROWS;
    int r1 = min(r0 + BROWS, N);
    int nrows = r1 - r0;
    const u32x2* mystg = stg + (size_t)b * MAXC;
    // stage my records in registers (single global read of stg)
    u32x2 myrec[10];
    int nmine = 0;
#pragma unroll
    for (int i = 0; i < 10; i++) {
        int idx = t + i * 1024;
        if (idx < cnt) { myrec[i] = mystg[idx]; nmine = i + 1; }
    }
    if (t < BROWS) s_c[t] = 0;
    __syncthreads();
#pragma unroll
    for (int i = 0; i < 10; i++)
        if (i < nmine) atomicAdd(&s_c[(int)myrec[i].y - r0], 1);
    __syncthreads();
    if (t < BROWS) s_x[t] = s_c[t];
    __syncthreads();
    for (int off = 1; off < BROWS; off <<= 1) {
        int v = 0;
        if (t < BROWS && t >= off) v = s_x[t - off];
        __syncthreads();
        if (t < BROWS) s_x[t] += v;
        __syncthreads();
    }
    // exclusive offsets -> row_ptr + per-row cursors
    if (t < nrows) {
        int excl = s_x[t] - s_c[t];
        row_ptr[r0 + t] = bbase + excl;
        s_c[t] = excl;
    }
    if (b == NB - 1 && t == 0) row_ptr[N] = bbase + cnt;
    __syncthreads();
    // scatter into sorted LDS order (from registers)
#pragma unroll
    for (int i = 0; i < 10; i++)
        if (i < nmine) {
            int slot = atomicAdd(&s_c[(int)myrec[i].y - r0], 1);
            s_out[slot] = myrec[i].x;
        }
    __syncthreads();
    for (int i = t; i < cnt; i += 1024)
        recs[bbase + i] = s_out[i];
}

// 4-edge clamped processing for one row: loads recs+h, lerps fv, accumulates.
#define PROC4(KK, SS, TT, ACC) do {                                          \
    int _lim = ((TT) > (SS)) ? (TT) - 1 : 0;                                 \
    int _ka = min((KK), _lim),     _kb = min((KK) + 1, _lim);                \
    int _kc = min((KK) + 2, _lim), _kd = min((KK) + 3, _lim);                \
    unsigned _ra = recs[_ka], _rb = recs[_kb];                               \
    unsigned _rc = recs[_kc], _rd = recs[_kd];                               \
    float _ta = (float)(_ra & 32767u) * (1.0f / 16.0f);                      \
    float _tb = (float)(_rb & 32767u) * (1.0f / 16.0f);                      \
    float _tc = (float)(_rc & 32767u) * (1.0f / 16.0f);                      \
    float _td = (float)(_rd & 32767u) * (1.0f / 16.0f);                      \
    int _ia = (int)_ta, _ib = (int)_tb, _ic = (int)_tc, _id = (int)_td;      \
    float _fa = s_lut[_ia], _fb = s_lut[_ib];                                \
    float _fc = s_lut[_ic], _fd = s_lut[_id];                                \
    float _va = _fa + (_ta - (float)_ia) * (s_lut[_ia + 1] - _fa);           \
    float _vb = _fb + (_tb - (float)_ib) * (s_lut[_ib + 1] - _fb);           \
    float _vc = _fc + (_tc - (float)_ic) * (s_lut[_ic + 1] - _fc);           \
    float _vd = _fd + (_td - (float)_id) * (s_lut[_id + 1] - _fd);           \
    _va = ((KK)     < (TT)) ? _va : 0.f;                                     \
    _vb = ((KK) + 1 < (TT)) ? _vb : 0.f;                                     \
    _vc = ((KK) + 2 < (TT)) ? _vc : 0.f;                                     \
    _vd = ((KK) + 3 < (TT)) ? _vd : 0.f;                                     \
    union { uint4 u; h2 v[4]; } _pa, _pb, _pc, _pd;                          \
    _pa.u = h4[(_ra >> 15) * 8u + (unsigned)ci];                             \
    _pb.u = h4[(_rb >> 15) * 8u + (unsigned)ci];                             \
    _pc.u = h4[(_rc >> 15) * 8u + (unsigned)ci];                             \
    _pd.u = h4[(_rd >> 15) * 8u + (unsigned)ci];                             \
    _Float16 _ha = (_Float16)_va, _hb = (_Float16)_vb;                       \
    _Float16 _hc = (_Float16)_vc, _hd = (_Float16)_vd;                       \
    h2 _aa = (h2){_ha, _ha}, _ab = (h2){_hb, _hb};                           \
    h2 _ac = (h2){_hc, _hc}, _ad = (h2){_hd, _hd};                           \
    _Pragma("unroll")                                                        \
    for (int _q = 0; _q < 4; _q++) (ACC)[_q] += _aa * _pa.v[_q];             \
    _Pragma("unroll")                                                        \
    for (int _q = 0; _q < 4; _q++) (ACC)[_q] += _ab * _pb.v[_q];             \
    _Pragma("unroll")                                                        \
    for (int _q = 0; _q < 4; _q++) (ACC)[_q] += _ac * _pc.v[_q];             \
    _Pragma("unroll")                                                        \
    for (int _q = 0; _q < 4; _q++) (ACC)[_q] += _ad * _pd.v[_q];             \
} while (0)

// Fused layer. Phase A: group-owns-TWO-rows interleaved — 8 groups x 8 lanes;
// each group walks BOTH its rows with 4-edge unroll each (8 independent
// rec->gather chains in flight per group). Phase B: 64x64x2 MLP as 16 MFMAs.
// last=1: skip h store, emit per-wave 64-channel partial sums for the mean.
__global__ __launch_bounds__(256, 6)
void k_layer(const int* __restrict__ row_ptr, const unsigned int* __restrict__ recs,
             const float* __restrict__ lutl, const h8* __restrict__ Wsw,
             const float* __restrict__ b1, const float* __restrict__ b2p,
             const _Float16* __restrict__ h_in, _Float16* __restrict__ h_out,
             float* __restrict__ pA, int N, int last) {
    __shared__ float s_lut[LUTN + 1];       // 8196 B
    __shared__ _Float16 sA[64 * ASTRIDE];   // 9216 B
    for (int i = threadIdx.x; i <= LUTN; i += 256) s_lut[i] = lutl[i];
    __syncthreads();

    int lane = threadIdx.x & 63;
    int w = threadIdx.x >> 6;
    int base = blockIdx.x * 64 + w * 16;    // this wave's 16 nodes
    int g = lane >> 3, ci = lane & 7;       // 8 groups x 8 lanes
    const uint4* h4 = (const uint4*)h_in;   // 8 halves per uint4; 8 per row

    // ---- phase A: two rows per group, interleaved ----
    {
        int node0 = base + g;
        int node1 = base + 8 + g;
        h2 acc0[4], acc1[4];
#pragma unroll
        for (int q = 0; q < 4; q++) {
            acc0[q] = (h2){(_Float16)0.f, (_Float16)0.f};
            acc1[q] = (h2){(_Float16)0.f, (_Float16)0.f};
        }
        int s0 = 0, t0 = 0, s1 = 0, t1 = 0;
        if (node0 < N) { s0 = row_ptr[node0]; t0 = row_ptr[node0 + 1]; }
        if (node1 < N) { s1 = row_ptr[node1]; t1 = row_ptr[node1 + 1]; }
        int it0 = (t0 - s0 + 3) >> 2;
        int it1 = (t1 - s1 + 3) >> 2;
        int iters = max(it0, it1);
        for (int it = 0; it < iters; ++it) {
            int k0 = s0 + it * 4;
            int k1 = s1 + it * 4;
            PROC4(k0, s0, t0, acc0);
            PROC4(k1, s1, t1, acc1);
        }
        union { uint4 u4; h2 v[4]; } pk;
#pragma unroll
        for (int q = 0; q < 4; q++) pk.v[q] = acc0[q];
        *(uint4*)&sA[(size_t)(w * 16 + g) * ASTRIDE + ci * 8] = pk.u4;
#pragma unroll
        for (int q = 0; q < 4; q++) pk.v[q] = acc1[q];
        *(uint4*)&sA[(size_t)(w * 16 + 8 + g) * ASTRIDE + ci * 8] = pk.u4;
    }
    // wave-private LDS rows: in-wave ds ordering, no barrier needed

    // ---- phase B: MFMA MLP ----
    int q4 = lane >> 4, c16 = lane & 15;
    int rowb = w * 16;
    const h8* WB1 = Wsw;            // frags [kt][nt][lane]
    const h8* WB2 = Wsw + 8 * 64;
    h8 A0 = *(const h8*)&sA[(size_t)(rowb + c16) * ASTRIDE + q4 * 8];
    h8 A1 = *(const h8*)&sA[(size_t)(rowb + c16) * ASTRIDE + 32 + q4 * 8];
    f32x4 C1[4];
#pragma unroll
    for (int nt = 0; nt < 4; nt++) {
        f32x4 c = {0.f, 0.f, 0.f, 0.f};
        c = __builtin_amdgcn_mfma_f32_16x16x32_f16(A0, WB1[nt * 64 + lane], c, 0, 0, 0);
        c = __builtin_amdgcn_mfma_f32_16x16x32_f16(A1, WB1[(4 + nt) * 64 + lane], c, 0, 0, 0);
        C1[nt] = c;
    }
#pragma unroll
    for (int nt = 0; nt < 4; nt++) {
        float bb = b1[nt * 16 + c16];
#pragma unroll
        for (int reg = 0; reg < 4; reg++) {
            float v = softplus_f(C1[nt][reg] + bb);
            sA[(size_t)(rowb + q4 * 4 + reg) * ASTRIDE + nt * 16 + c16] = (_Float16)v;
        }
    }
    h8 M0 = *(const h8*)&sA[(size_t)(rowb + c16) * ASTRIDE + q4 * 8];
    h8 M1 = *(const h8*)&sA[(size_t)(rowb + c16) * ASTRIDE + 32 + q4 * 8];
    f32x4 C2[4];
#pragma unroll
    for (int nt = 0; nt < 4; nt++) {
        f32x4 c = {0.f, 0.f, 0.f, 0.f};
        c = __builtin_amdgcn_mfma_f32_16x16x32_f16(M0, WB2[nt * 64 + lane], c, 0, 0, 0);
        c = __builtin_amdgcn_mfma_f32_16x16x32_f16(M1, WB2[(4 + nt) * 64 + lane], c, 0, 0, 0);
        C2[nt] = c;
    }
    // epilogue: + b2' (BN folded), fp16 residual
    if (!last) {
#pragma unroll
        for (int nt = 0; nt < 4; nt++) {
            float bb2 = b2p[nt * 16 + c16];
#pragma unroll
            for (int reg = 0; reg < 4; reg++) {
                int node = base + q4 * 4 + reg;
                if (node < N) {
                    size_t idx = (size_t)node * H + nt * 16 + c16;
                    float hn = (float)h_in[idx] + C2[nt][reg] + bb2;
                    h_out[idx] = (_Float16)hn;
                }
            }
        }
    } else {
        // last layer: per-wave column partial sums (no h store)
        float ps[4];
#pragma unroll
        for (int nt = 0; nt < 4; nt++) {
            float bb2 = b2p[nt * 16 + c16];
            float s = 0.f;
#pragma unroll
            for (int reg = 0; reg < 4; reg++) {
                int node = base + q4 * 4 + reg;
                if (node < N) {
                    size_t idx = (size_t)node * H + nt * 16 + c16;
                    s += (float)h_in[idx] + C2[nt][reg] + bb2;
                }
            }
            ps[nt] = s;
        }
#pragma unroll
        for (int nt = 0; nt < 4; nt++) {
            float v = ps[nt];
            v += __shfl_xor(v, 16, 64);
            v += __shfl_xor(v, 32, 64);
            if (lane < 16)
                pA[((size_t)blockIdx.x * 4 + w) * H + nt * 16 + c16] = v;
        }
    }
}

// Stage 1 of mean: reduce per-wave partials (P rows) to MEANB rows.
__global__ __launch_bounds__(256)
void k_mean(const float* __restrict__ pA, float* __restrict__ partials, int P) {
    __shared__ float s_r[4][H];
    int lane = threadIdx.x & 63;
    int w = threadIdx.x >> 6;
    int wg = blockIdx.x * 4 + w;
    int stride = gridDim.x * 4;
    float local = 0.f;
    for (int i = wg; i < P; i += stride) local += pA[(size_t)i * H + lane];
    s_r[w][lane] = local;
    __syncthreads();
    if (w == 0) {
        float s = s_r[0][lane] + s_r[1][lane] + s_r[2][lane] + s_r[3][lane];
        partials[(size_t)blockIdx.x * H + lane] = s;
    }
}

// Stage 2: one block reduces MEANB partial rows, then the tiny output MLP.
__global__ __launch_bounds__(256)
void k_final(const float* __restrict__ partials, int N,
             const float* __restrict__ oW1, const float* __restrict__ ob1,
             const float* __restrict__ og1, const float* __restrict__ obt1,
             const float* __restrict__ oW2, const float* __restrict__ ob2,
             const float* __restrict__ og2, const float* __restrict__ obt2,
             const float* __restrict__ fin_W, const float* __restrict__ fin_b,
             float* __restrict__ out) {
    __shared__ float red[4][H];
    __shared__ float sg[H], su[H / 2], sv[H / 2];
    int t = threadIdx.x;
    int ch = t & 63, grp = t >> 6;
    float s = 0.f;
    for (int b = grp; b < MEANB; b += 4) s += partials[(size_t)b * H + ch];
    red[grp][ch] = s;
    __syncthreads();
    if (t < H) sg[t] = (red[0][t] + red[1][t] + red[2][t] + red[3][t]) / (float)N;
    __syncthreads();
    int j = t;
    if (j < H / 2) {
        float acc = ob1[j];
        for (int k = 0; k < H; k++) acc += sg[k] * oW1[k * (H / 2) + j];
        su[j] = softplus_f(acc) * BN_INV * og1[j] + obt1[j];
    }
    __syncthreads();
    if (j < H / 2) {
        float acc = ob2[j];
        for (int k = 0; k < H / 2; k++) acc += su[k] * oW2[k * (H / 2) + j];
        sv[j] = softplus_f(acc) * BN_INV * og2[j] + obt2[j];
    }
    __syncthreads();
    if (j < 3) {
        float acc = fin_b[j];
        for (int k = 0; k < H / 2; k++) acc += sv[k] * fin_W[k * 3 + j];
        out[j] = acc;
    }
}

extern "C" void kernel_launch(void* const* d_in, const int* in_sizes, int n_in,
                              void* d_out, int out_size, void* d_ws, size_t ws_size,
                              hipStream_t stream) {
    const float* x      = (const float*)d_in[0];
    const int*   ei     = (const int*)d_in[1];
    const float* dist   = (const float*)d_in[2];
    /* d_in[3] edge_attr: unused by reference */
    const float* emb_W  = (const float*)d_in[4];
    const float* emb_b  = (const float*)d_in[5];
    const float* fW1    = (const float*)d_in[6];
    const float* fb1    = (const float*)d_in[7];
    const float* fW2    = (const float*)d_in[8];
    const float* fb2    = (const float*)d_in[9];
    const float* iW1    = (const float*)d_in[10];
    const float* ib1    = (const float*)d_in[11];
    const float* iW2    = (const float*)d_in[12];
    const float* ib2    = (const float*)d_in[13];
    const float* bn_g   = (const float*)d_in[14];
    const float* bn_b   = (const float*)d_in[15];
    const float* oW1    = (const float*)d_in[16];
    const float* ob1    = (const float*)d_in[17];
    const float* og1    = (const float*)d_in[18];
    const float* obt1   = (const float*)d_in[19];
    const float* oW2    = (const float*)d_in[20];
    const float* ob2    = (const float*)d_in[21];
    const float* og2    = (const float*)d_in[22];
    const float* obt2   = (const float*)d_in[23];
    const float* fin_W  = (const float*)d_in[24];
    const float* fin_b  = (const float*)d_in[25];
    float* out = (float*)d_out;

    int N = in_sizes[0] / FIN;
    int E = in_sizes[2];
    int NB = (N + BROWS - 1) / BROWS;          // sort buckets (196 @ N=100k)
    int nb_tile = (N + 63) / 64;
    int P = nb_tile * 4;                       // per-wave partial rows

    // workspace layout (16B-aligned chunks first)
    float*  ws   = (float*)d_ws;
    _Float16* h0 = (_Float16*)ws;                          // N*H fp16
    _Float16* h1 = h0 + (size_t)N * H;                     // N*H fp16
    unsigned int* recs = (unsigned int*)(h1 + (size_t)N * H);    // E uint32
    h8*     Wsw  = (h8*)(recs + E);                        // 3*2*8*64 h8
    float*  lut  = (float*)(Wsw + NLAYERS * 2 * 8 * 64);   // 3*LUTSTRIDE
    float*  partials = lut + 3 * LUTSTRIDE;                // MEANB*H
    float*  b2p  = partials + MEANB * H;                   // L*H
    float*  pA   = b2p + NLAYERS * H;                      // P*H
    u32x2*  stg  = (u32x2*)(pA + (size_t)P * H);           // NBMAX*MAXC u32x2
    int*    row_ptr = (int*)(stg + (size_t)NBMAX * MAXC);  // N+1
    unsigned int* cursor = (unsigned int*)(row_ptr + N + 1);     // NBMAX

    hipMemsetAsync(cursor, 0, NBMAX * sizeof(unsigned int), stream);

    int nbA = (E + ABLK - 1) / ABLK;
    int nbE16 = (N + 15) / 16;
    int nb_pre = nbA + nbE16 + NLAYERS * 3 + 3;
    k_pre<<<nb_pre, 1024, 0, stream>>>(x, emb_W, emb_b, h0,
                                       fW1, fb1, fW2, fb2, iW1, iW2,
                                       bn_g, bn_b, ib2, Wsw, b2p, lut,
                                       ei, dist, cursor, stg,
                                       N, E, NB, nbA, nbE16);

    k_passB<<<NB, 1024, 0, stream>>>(stg, cursor, row_ptr, recs, N, NB);

    _Float16* hp[2] = {h0, h1};
    for (int l = 0; l < NLAYERS; l++) {
        k_layer<<<nb_tile, 256, 0, stream>>>(row_ptr, recs, lut + (size_t)l * LUTSTRIDE,
                                             Wsw + (size_t)l * 1024,
                                             ib1 + l * H, b2p + l * H,
                                             hp[l & 1], hp[(l + 1) & 1], pA, N,
                                             (l == NLAYERS - 1) ? 1 : 0);
    }

    k_mean<<<MEANB, 256, 0, stream>>>(pA, partials, P);
    k_final<<<1, 256, 0, stream>>>(partials, N, oW1, ob1, og1, obt1,
                                   oW2, ob2, og2, obt2, fin_W, fin_b, out);
}

// Round 11
// 325.579 us; speedup vs baseline: 1.2574x; 1.0181x over previous
//
#include <hip/hip_runtime.h>
#include <hip/hip_fp16.h>
#include <math.h>

#define CUTOFF 5.0f
#define H 64
#define FIN 16
#define NLAYERS 3
#define LUTN 2048          // intervals; table has LUTN+1 entries
#define LUTSTRIDE 2052     // padded per-layer stride
#define ASTRIDE 72         // LDS row stride in halves (144B, 16B-aligned)
#define MEANB 256          // blocks in mean pass (partials rows)
#define BROWS 512          // rows per sort bucket (== 1<<9)
#define NBMAX 256          // max buckets (N <= 128K)
#define MAXC 10240         // per-bucket stg stride AND LDS sort capacity (40KB)
#define ABLK 4096          // edges per pass-A block

// 1/sqrt(1 + 1e-3)  (BN inference, moving mean 0 / var 1)
#define BN_INV 0.999500374750f

typedef _Float16 h8 __attribute__((ext_vector_type(8)));
typedef _Float16 h2 __attribute__((ext_vector_type(2)));
typedef float f32x4 __attribute__((ext_vector_type(4)));
typedef unsigned int u32x2 __attribute__((ext_vector_type(2)));

__device__ __forceinline__ float softplus_f(float x) {
    return fmaxf(x, 0.f) + __logf(1.f + __expf(-fabsf(x)));
}

// ---- K_pre: fused passA + setup. Block roles by blockIdx range:
//   [0, nbA)             passA: LDS-sorted bucket scatter (coalesced write-out)
//   [nbA, +nbE16)        embed 16 nodes/block -> h0 fp16
//   [.., +9)             LUT: inline wsum/bsum, 1024 entries/block
//   [.., +3)             weight swizzle Wsw + b2p
__global__ __launch_bounds__(1024)
void k_pre(const float* __restrict__ x, const float* __restrict__ emb_W,
           const float* __restrict__ emb_b, _Float16* __restrict__ h0,
           const float* __restrict__ fW1, const float* __restrict__ fb1,
           const float* __restrict__ fW2, const float* __restrict__ fb2,
           const float* __restrict__ iW1, const float* __restrict__ iW2,
           const float* __restrict__ bn_g, const float* __restrict__ bn_b,
           const float* __restrict__ ib2, h8* __restrict__ Wsw,
           float* __restrict__ b2p, float* __restrict__ lut,
           const int* __restrict__ ei, const float* __restrict__ dist,
           unsigned int* __restrict__ cursor, u32x2* __restrict__ stg,
           int N, int E, int NB, int nbA, int nbE16) {
    __shared__ u32x2 s_rec[ABLK];          // 32KB block-local sorted records
    __shared__ unsigned s_cnt[NBMAX];      // per-bucket counts
    __shared__ unsigned s_x[NBMAX];        // inclusive scan
    __shared__ unsigned s_ofs[NBMAX];      // scatter cursors
    __shared__ unsigned s_gbase[NBMAX];    // global bases (cursor-reserved)
    __shared__ float swsum[64];
    __shared__ float sbsum;
    int b = blockIdx.x;
    int t = threadIdx.x;
    if (b < nbA) {
        // ---- passA role: LDS sort by bucket, then coalesced-run write-out ----
        int e0 = b * ABLK;
        int nE = min(ABLK, E - e0);
        for (int i = t; i < NBMAX; i += 1024) s_cnt[i] = 0;
        __syncthreads();
        int rowv[4];
        unsigned rxv[4] = {0u, 0u, 0u, 0u};
#pragma unroll
        for (int j = 0; j < 4; j++) {
            int li = j * 1024 + t;
            rowv[j] = -1;
            if (li < nE) {
                int e = e0 + li;
                int r = ei[e];
                int col = ei[E + e];
                float d = dist[e];
                int didx = (int)(d * (32768.0f / CUTOFF) + 0.5f);
                didx = max(0, min(didx, 32767));
                rowv[j] = r;
                rxv[j] = ((unsigned)col << 15) | (unsigned)didx;
                atomicAdd(&s_cnt[r / BROWS], 1u);
            }
        }
        __syncthreads();
        if (t < NBMAX) s_x[t] = s_cnt[t];
        __syncthreads();
        for (int off = 1; off < NBMAX; off <<= 1) {
            unsigned v = 0;
            if (t < NBMAX && t >= off) v = s_x[t - off];
            __syncthreads();
            if (t < NBMAX) s_x[t] += v;
            __syncthreads();
        }
        if (t < NBMAX) {
            unsigned c = s_cnt[t];
            unsigned lstart = s_x[t] - c;
            s_ofs[t] = lstart;
            s_x[t] = lstart;                       // repurpose as lstart
            s_gbase[t] = (c && t < (unsigned)NB) ? atomicAdd(&cursor[t], c) : 0u;
        }
        __syncthreads();
#pragma unroll
        for (int j = 0; j < 4; j++) {
            if (rowv[j] >= 0) {
                unsigned slot = atomicAdd(&s_ofs[rowv[j] / BROWS], 1u);
                u32x2 rec;
                rec.x = rxv[j];
                rec.y = (unsigned)rowv[j];
                s_rec[slot] = rec;
            }
        }
        __syncthreads();
        // linear walk of sorted records -> per-bucket contiguous global runs
        for (int i = t; i < nE; i += 1024) {
            u32x2 rec = s_rec[i];
            int bk = (int)(rec.y / BROWS);
            unsigned g = s_gbase[bk] + ((unsigned)i - s_x[bk]);
            if (g < MAXC)                          // overflow guard (~never)
                stg[(size_t)bk * MAXC + g] = rec;
        }
    } else if (b < nbA + nbE16) {
        // ---- embed role: 16 nodes/block ----
        int lane = t & 63;
        int w = t >> 6;
        int node = (b - nbA) * 16 + w;
        if (node < N) {
            float acc = emb_b[lane];
#pragma unroll
            for (int k = 0; k < FIN; k++) acc += x[node * FIN + k] * emb_W[k * H + lane];
            h0[(size_t)node * H + lane] = (_Float16)acc;
        }
    } else if (b < nbA + nbE16 + NLAYERS * 3) {
        // ---- LUT role ----
        int lb = b - nbA - nbE16;
        int l = lb / 3, part = lb % 3;
        if (t < 64) {
            float s = 0.f;
            for (int j = 0; j < H; j++) s += fW2[l * H * H + t * H + j];
            swsum[t] = s;
        }
        if (t == 64) {
            float s = 0.f;
            for (int j = 0; j < H; j++) s += fb2[l * H + j];
            sbsum = s;
        }
        __syncthreads();
        int i = part * 1024 + t;
        if (i <= LUTN) {
            float d = (float)i * (CUTOFF / (float)LUTN);
            float scaled = d * (2.0f / CUTOFF) - 1.0f;
            float cut = 0.5f * (__cosf(d * (3.14159265358979f / CUTOFF)) + 1.0f);
            if (d > CUTOFF) cut = 0.f;
            float s = 0.f;
            for (int hh = 0; hh < H; hh++) {
                int wi = l * H + hh;
                s += tanhf(scaled * fW1[wi] + fb1[wi]) * swsum[hh];
            }
            lut[l * LUTSTRIDE + i] = cut * (s + sbsum);
        }
    } else {
        // ---- weight swizzle role ----
        int tid = (b - nbA - nbE16 - NLAYERS * 3) * 1024 + t;
        if (tid < NLAYERS * H)
            b2p[tid] = ib2[tid] * BN_INV * bn_g[tid] + bn_b[tid];
        if (tid < NLAYERS * 2 * 8 * 64) {
            int lane = tid & 63;
            int frag = (tid >> 6) & 7;
            int mat  = (tid >> 9) & 1;
            int l    = tid >> 10;
            int kt = frag >> 2, nt = frag & 3;
            int n = nt * 16 + (lane & 15);
            int k0 = kt * 32 + (lane >> 4) * 8;
            const float* W = (mat ? iW2 : iW1) + l * H * H;
            float scale = mat ? BN_INV * bn_g[l * H + n] : 1.0f;
            h8 v;
#pragma unroll
            for (int j = 0; j < 8; j++) v[j] = (_Float16)(W[(k0 + j) * H + n] * scale);
            Wsw[tid] = v;
        }
    }
}

// Pass B: self-contained per-bucket counting sort + row_ptr production.
// Single stg read: each thread stages its <=10 records in registers
// (static-index unroll), counts via LDS atomics, scans, scatters from regs.
__global__ __launch_bounds__(1024)
void k_passB(const u32x2* __restrict__ stg, const unsigned int* __restrict__ cursor,
             int* __restrict__ row_ptr, unsigned int* __restrict__ recs,
             int N, int NB) {
    __shared__ int s_bb[NBMAX];
    __shared__ int s_c[BROWS];
    __shared__ int s_x[BROWS];
    __shared__ unsigned s_out[MAXC];
    int b = blockIdx.x, t = threadIdx.x;
    // bucket counts + redundant inclusive scan over NBMAX
    if (t < NBMAX) {
        int cb = 0;
        if (t < NB) cb = min((int)cursor[t], MAXC);
        s_bb[t] = cb;
    }
    __syncthreads();
    for (int off = 1; off < NBMAX; off <<= 1) {
        int v = 0;
        if (t < NBMAX && t >= off) v = s_bb[t - off];
        __syncthreads();
        if (t < NBMAX) s_bb[t] += v;
        __syncthreads();
    }
    int bbase = (b > 0) ? s_bb[b - 1] : 0;
    int cnt = s_bb[b] - bbase;
    int r0 = b * BROWS;
    int r1 = min(r0 + BROWS, N);
    int nrows = r1 - r0;
    const u32x2* mystg = stg + (size_t)b * MAXC;
    // stage my records in registers (single global read of stg)
    u32x2 myrec[10];
    int nmine = 0;
#pragma unroll
    for (int i = 0; i < 10; i++) {
        int idx = t + i * 1024;
        if (idx < cnt) { myrec[i] = mystg[idx]; nmine = i + 1; }
    }
    if (t < BROWS) s_c[t] = 0;
    __syncthreads();
#pragma unroll
    for (int i = 0; i < 10; i++)
        if (i < nmine) atomicAdd(&s_c[(int)myrec[i].y - r0], 1);
    __syncthreads();
    if (t < BROWS) s_x[t] = s_c[t];
    __syncthreads();
    for (int off = 1; off < BROWS; off <<= 1) {
        int v = 0;
        if (t < BROWS && t >= off) v = s_x[t - off];
        __syncthreads();
        if (t < BROWS) s_x[t] += v;
        __syncthreads();
    }
    // exclusive offsets -> row_ptr + per-row cursors
    if (t < nrows) {
        int excl = s_x[t] - s_c[t];
        row_ptr[r0 + t] = bbase + excl;
        s_c[t] = excl;
    }
    if (b == NB - 1 && t == 0) row_ptr[N] = bbase + cnt;
    __syncthreads();
    // scatter into sorted LDS order (from registers)
#pragma unroll
    for (int i = 0; i < 10; i++)
        if (i < nmine) {
            int slot = atomicAdd(&s_c[(int)myrec[i].y - r0], 1);
            s_out[slot] = myrec[i].x;
        }
    __syncthreads();
    for (int i = t; i < cnt; i += 1024)
        recs[bbase + i] = s_out[i];
}

// 4-edge clamped processing for one row: loads recs+h, lerps fv, accumulates.
#define PROC4(KK, SS, TT, ACC) do {                                          \
    int _lim = ((TT) > (SS)) ? (TT) - 1 : 0;                                 \
    int _ka = min((KK), _lim),     _kb = min((KK) + 1, _lim);                \
    int _kc = min((KK) + 2, _lim), _kd = min((KK) + 3, _lim);                \
    unsigned _ra = recs[_ka], _rb = recs[_kb];                               \
    unsigned _rc = recs[_kc], _rd = recs[_kd];                               \
    float _ta = (float)(_ra & 32767u) * (1.0f / 16.0f);                      \
    float _tb = (float)(_rb & 32767u) * (1.0f / 16.0f);                      \
    float _tc = (float)(_rc & 32767u) * (1.0f / 16.0f);                      \
    float _td = (float)(_rd & 32767u) * (1.0f / 16.0f);                      \
    int _ia = (int)_ta, _ib = (int)_tb, _ic = (int)_tc, _id = (int)_td;      \
    float _fa = s_lut[_ia], _fb = s_lut[_ib];                                \
    float _fc = s_lut[_ic], _fd = s_lut[_id];                                \
    float _va = _fa + (_ta - (float)_ia) * (s_lut[_ia + 1] - _fa);           \
    float _vb = _fb + (_tb - (float)_ib) * (s_lut[_ib + 1] - _fb);           \
    float _vc = _fc + (_tc - (float)_ic) * (s_lut[_ic + 1] - _fc);           \
    float _vd = _fd + (_td - (float)_id) * (s_lut[_id + 1] - _fd);           \
    _va = ((KK)     < (TT)) ? _va : 0.f;                                     \
    _vb = ((KK) + 1 < (TT)) ? _vb : 0.f;                                     \
    _vc = ((KK) + 2 < (TT)) ? _vc : 0.f;                                     \
    _vd = ((KK) + 3 < (TT)) ? _vd : 0.f;                                     \
    union { uint4 u; h2 v[4]; } _pa, _pb, _pc, _pd;                          \
    _pa.u = h4[(_ra >> 15) * 8u + (unsigned)ci];                             \
    _pb.u = h4[(_rb >> 15) * 8u + (unsigned)ci];                             \
    _pc.u = h4[(_rc >> 15) * 8u + (unsigned)ci];                             \
    _pd.u = h4[(_rd >> 15) * 8u + (unsigned)ci];                             \
    _Float16 _ha = (_Float16)_va, _hb = (_Float16)_vb;                       \
    _Float16 _hc = (_Float16)_vc, _hd = (_Float16)_vd;                       \
    h2 _aa = (h2){_ha, _ha}, _ab = (h2){_hb, _hb};                           \
    h2 _ac = (h2){_hc, _hc}, _ad = (h2){_hd, _hd};                           \
    _Pragma("unroll")                                                        \
    for (int _q = 0; _q < 4; _q++) (ACC)[_q] += _aa * _pa.v[_q];             \
    _Pragma("unroll")                                                        \
    for (int _q = 0; _q < 4; _q++) (ACC)[_q] += _ab * _pb.v[_q];             \
    _Pragma("unroll")                                                        \
    for (int _q = 0; _q < 4; _q++) (ACC)[_q] += _ac * _pc.v[_q];             \
    _Pragma("unroll")                                                        \
    for (int _q = 0; _q < 4; _q++) (ACC)[_q] += _ad * _pd.v[_q];             \
} while (0)

// Fused layer. Phase A: group-owns-TWO-rows interleaved — 8 groups x 8 lanes;
// each group walks BOTH its rows with 4-edge unroll each (8 independent
// rec->gather chains in flight per group). Phase B: 64x64x2 MLP as 16 MFMAs.
// last=1: skip h store, emit per-wave 64-channel partial sums for the mean.
__global__ __launch_bounds__(256, 6)
void k_layer(const int* __restrict__ row_ptr, const unsigned int* __restrict__ recs,
             const float* __restrict__ lutl, const h8* __restrict__ Wsw,
             const float* __restrict__ b1, const float* __restrict__ b2p,
             const _Float16* __restrict__ h_in, _Float16* __restrict__ h_out,
             float* __restrict__ pA, int N, int last) {
    __shared__ float s_lut[LUTN + 1];       // 8196 B
    __shared__ _Float16 sA[64 * ASTRIDE];   // 9216 B
    for (int i = threadIdx.x; i <= LUTN; i += 256) s_lut[i] = lutl[i];
    __syncthreads();

    int lane = threadIdx.x & 63;
    int w = threadIdx.x >> 6;
    int base = blockIdx.x * 64 + w * 16;    // this wave's 16 nodes
    int g = lane >> 3, ci = lane & 7;       // 8 groups x 8 lanes
    const uint4* h4 = (const uint4*)h_in;   // 8 halves per uint4; 8 per row

    // ---- phase A: two rows per group, interleaved ----
    {
        int node0 = base + g;
        int node1 = base + 8 + g;
        h2 acc0[4], acc1[4];
#pragma unroll
        for (int q = 0; q < 4; q++) {
            acc0[q] = (h2){(_Float16)0.f, (_Float16)0.f};
            acc1[q] = (h2){(_Float16)0.f, (_Float16)0.f};
        }
        int s0 = 0, t0 = 0, s1 = 0, t1 = 0;
        if (node0 < N) { s0 = row_ptr[node0]; t0 = row_ptr[node0 + 1]; }
        if (node1 < N) { s1 = row_ptr[node1]; t1 = row_ptr[node1 + 1]; }
        int it0 = (t0 - s0 + 3) >> 2;
        int it1 = (t1 - s1 + 3) >> 2;
        int iters = max(it0, it1);
        for (int it = 0; it < iters; ++it) {
            int k0 = s0 + it * 4;
            int k1 = s1 + it * 4;
            PROC4(k0, s0, t0, acc0);
            PROC4(k1, s1, t1, acc1);
        }
        union { uint4 u4; h2 v[4]; } pk;
#pragma unroll
        for (int q = 0; q < 4; q++) pk.v[q] = acc0[q];
        *(uint4*)&sA[(size_t)(w * 16 + g) * ASTRIDE + ci * 8] = pk.u4;
#pragma unroll
        for (int q = 0; q < 4; q++) pk.v[q] = acc1[q];
        *(uint4*)&sA[(size_t)(w * 16 + 8 + g) * ASTRIDE + ci * 8] = pk.u4;
    }
    // wave-private LDS rows: in-wave ds ordering, no barrier needed

    // ---- phase B: MFMA MLP ----
    int q4 = lane >> 4, c16 = lane & 15;
    int rowb = w * 16;
    const h8* WB1 = Wsw;            // frags [kt][nt][lane]
    const h8* WB2 = Wsw + 8 * 64;
    h8 A0 = *(const h8*)&sA[(size_t)(rowb + c16) * ASTRIDE + q4 * 8];
    h8 A1 = *(const h8*)&sA[(size_t)(rowb + c16) * ASTRIDE + 32 + q4 * 8];
    f32x4 C1[4];
#pragma unroll
    for (int nt = 0; nt < 4; nt++) {
        f32x4 c = {0.f, 0.f, 0.f, 0.f};
        c = __builtin_amdgcn_mfma_f32_16x16x32_f16(A0, WB1[nt * 64 + lane], c, 0, 0, 0);
        c = __builtin_amdgcn_mfma_f32_16x16x32_f16(A1, WB1[(4 + nt) * 64 + lane], c, 0, 0, 0);
        C1[nt] = c;
    }
#pragma unroll
    for (int nt = 0; nt < 4; nt++) {
        float bb = b1[nt * 16 + c16];
#pragma unroll
        for (int reg = 0; reg < 4; reg++) {
            float v = softplus_f(C1[nt][reg] + bb);
            sA[(size_t)(rowb + q4 * 4 + reg) * ASTRIDE + nt * 16 + c16] = (_Float16)v;
        }
    }
    h8 M0 = *(const h8*)&sA[(size_t)(rowb + c16) * ASTRIDE + q4 * 8];
    h8 M1 = *(const h8*)&sA[(size_t)(rowb + c16) * ASTRIDE + 32 + q4 * 8];
    f32x4 C2[4];
#pragma unroll
    for (int nt = 0; nt < 4; nt++) {
        f32x4 c = {0.f, 0.f, 0.f, 0.f};
        c = __builtin_amdgcn_mfma_f32_16x16x32_f16(M0, WB2[nt * 64 + lane], c, 0, 0, 0);
        c = __builtin_amdgcn_mfma_f32_16x16x32_f16(M1, WB2[(4 + nt) * 64 + lane], c, 0, 0, 0);
        C2[nt] = c;
    }
    // epilogue: + b2' (BN folded), fp16 residual
    if (!last) {
#pragma unroll
        for (int nt = 0; nt < 4; nt++) {
            float bb2 = b2p[nt * 16 + c16];
#pragma unroll
            for (int reg = 0; reg < 4; reg++) {
                int node = base + q4 * 4 + reg;
                if (node < N) {
                    size_t idx = (size_t)node * H + nt * 16 + c16;
                    float hn = (float)h_in[idx] + C2[nt][reg] + bb2;
                    h_out[idx] = (_Float16)hn;
                }
            }
        }
    } else {
        // last layer: per-wave column partial sums (no h store)
        float ps[4];
#pragma unroll
        for (int nt = 0; nt < 4; nt++) {
            float bb2 = b2p[nt * 16 + c16];
            float s = 0.f;
#pragma unroll
            for (int reg = 0; reg < 4; reg++) {
                int node = base + q4 * 4 + reg;
                if (node < N) {
                    size_t idx = (size_t)node * H + nt * 16 + c16;
                    s += (float)h_in[idx] + C2[nt][reg] + bb2;
                }
            }
            ps[nt] = s;
        }
#pragma unroll
        for (int nt = 0; nt < 4; nt++) {
            float v = ps[nt];
            v += __shfl_xor(v, 16, 64);
            v += __shfl_xor(v, 32, 64);
            if (lane < 16)
                pA[((size_t)blockIdx.x * 4 + w) * H + nt * 16 + c16] = v;
        }
    }
}

// Stage 1 of mean: reduce per-wave partials (P rows) to MEANB rows.
__global__ __launch_bounds__(256)
void k_mean(const float* __restrict__ pA, float* __restrict__ partials, int P) {
    __shared__ float s_r[4][H];
    int lane = threadIdx.x & 63;
    int w = threadIdx.x >> 6;
    int wg = blockIdx.x * 4 + w;
    int stride = gridDim.x * 4;
    float local = 0.f;
    for (int i = wg; i < P; i += stride) local += pA[(size_t)i * H + lane];
    s_r[w][lane] = local;
    __syncthreads();
    if (w == 0) {
        float s = s_r[0][lane] + s_r[1][lane] + s_r[2][lane] + s_r[3][lane];
        partials[(size_t)blockIdx.x * H + lane] = s;
    }
}

// Stage 2: one block reduces MEANB partial rows, then the tiny output MLP.
__global__ __launch_bounds__(256)
void k_final(const float* __restrict__ partials, int N,
             const float* __restrict__ oW1, const float* __restrict__ ob1,
             const float* __restrict__ og1, const float* __restrict__ obt1,
             const float* __restrict__ oW2, const float* __restrict__ ob2,
             const float* __restrict__ og2, const float* __restrict__ obt2,
             const float* __restrict__ fin_W, const float* __restrict__ fin_b,
             float* __restrict__ out) {
    __shared__ float red[4][H];
    __shared__ float sg[H], su[H / 2], sv[H / 2];
    int t = threadIdx.x;
    int ch = t & 63, grp = t >> 6;
    float s = 0.f;
    for (int b = grp; b < MEANB; b += 4) s += partials[(size_t)b * H + ch];
    red[grp][ch] = s;
    __syncthreads();
    if (t < H) sg[t] = (red[0][t] + red[1][t] + red[2][t] + red[3][t]) / (float)N;
    __syncthreads();
    int j = t;
    if (j < H / 2) {
        float acc = ob1[j];
        for (int k = 0; k < H; k++) acc += sg[k] * oW1[k * (H / 2) + j];
        su[j] = softplus_f(acc) * BN_INV * og1[j] + obt1[j];
    }
    __syncthreads();
    if (j < H / 2) {
        float acc = ob2[j];
        for (int k = 0; k < H / 2; k++) acc += su[k] * oW2[k * (H / 2) + j];
        sv[j] = softplus_f(acc) * BN_INV * og2[j] + obt2[j];
    }
    __syncthreads();
    if (j < 3) {
        float acc = fin_b[j];
        for (int k = 0; k < H / 2; k++) acc += sv[k] * fin_W[k * 3 + j];
        out[j] = acc;
    }
}

extern "C" void kernel_launch(void* const* d_in, const int* in_sizes, int n_in,
                              void* d_out, int out_size, void* d_ws, size_t ws_size,
                              hipStream_t stream) {
    const float* x      = (const float*)d_in[0];
    const int*   ei     = (const int*)d_in[1];
    const float* dist   = (const float*)d_in[2];
    /* d_in[3] edge_attr: unused by reference */
    const float* emb_W  = (const float*)d_in[4];
    const float* emb_b  = (const float*)d_in[5];
    const float* fW1    = (const float*)d_in[6];
    const float* fb1    = (const float*)d_in[7];
    const float* fW2    = (const float*)d_in[8];
    const float* fb2    = (const float*)d_in[9];
    const float* iW1    = (const float*)d_in[10];
    const float* ib1    = (const float*)d_in[11];
    const float* iW2    = (const float*)d_in[12];
    const float* ib2    = (const float*)d_in[13];
    const float* bn_g   = (const float*)d_in[14];
    const float* bn_b   = (const float*)d_in[15];
    const float* oW1    = (const float*)d_in[16];
    const float* ob1    = (const float*)d_in[17];
    const float* og1    = (const float*)d_in[18];
    const float* obt1   = (const float*)d_in[19];
    const float* oW2    = (const float*)d_in[20];
    const float* ob2    = (const float*)d_in[21];
    const float* og2    = (const float*)d_in[22];
    const float* obt2   = (const float*)d_in[23];
    const float* fin_W  = (const float*)d_in[24];
    const float* fin_b  = (const float*)d_in[25];
    float* out = (float*)d_out;

    int N = in_sizes[0] / FIN;
    int E = in_sizes[2];
    int NB = (N + BROWS - 1) / BROWS;          // sort buckets (196 @ N=100k)
    int nb_tile = (N + 63) / 64;
    int P = nb_tile * 4;                       // per-wave partial rows

    // workspace layout (16B-aligned chunks first)
    float*  ws   = (float*)d_ws;
    _Float16* h0 = (_Float16*)ws;                          // N*H fp16
    _Float16* h1 = h0 + (size_t)N * H;                     // N*H fp16
    unsigned int* recs = (unsigned int*)(h1 + (size_t)N * H);    // E uint32
    h8*     Wsw  = (h8*)(recs + E);                        // 3*2*8*64 h8
    float*  lut  = (float*)(Wsw + NLAYERS * 2 * 8 * 64);   // 3*LUTSTRIDE
    float*  partials = lut + 3 * LUTSTRIDE;                // MEANB*H
    float*  b2p  = partials + MEANB * H;                   // L*H
    float*  pA   = b2p + NLAYERS * H;                      // P*H
    u32x2*  stg  = (u32x2*)(pA + (size_t)P * H);           // NBMAX*MAXC u32x2
    int*    row_ptr = (int*)(stg + (size_t)NBMAX * MAXC);  // N+1
    unsigned int* cursor = (unsigned int*)(row_ptr + N + 1);     // NBMAX

    hipMemsetAsync(cursor, 0, NBMAX * sizeof(unsigned int), stream);

    int nbA = (E + ABLK - 1) / ABLK;
    int nbE16 = (N + 15) / 16;
    int nb_pre = nbA + nbE16 + NLAYERS * 3 + 3;
    k_pre<<<nb_pre, 1024, 0, stream>>>(x, emb_W, emb_b, h0,
                                       fW1, fb1, fW2, fb2, iW1, iW2,
                                       bn_g, bn_b, ib2, Wsw, b2p, lut,
                                       ei, dist, cursor, stg,
                                       N, E, NB, nbA, nbE16);

    k_passB<<<NB, 1024, 0, stream>>>(stg, cursor, row_ptr, recs, N, NB);

    _Float16* hp[2] = {h0, h1};
    for (int l = 0; l < NLAYERS; l++) {
        k_layer<<<nb_tile, 256, 0, stream>>>(row_ptr, recs, lut + (size_t)l * LUTSTRIDE,
                                             Wsw + (size_t)l * 1024,
                                             ib1 + l * H, b2p + l * H,
                                             hp[l & 1], hp[(l + 1) & 1], pA, N,
                                             (l == NLAYERS - 1) ? 1 : 0);
    }

    k_mean<<<MEANB, 256, 0, stream>>>(pA, partials, P);
    k_final<<<1, 256, 0, stream>>>(partials, N, oW1, ob1, og1, obt1,
                                   oW2, ob2, og2, obt2, fin_W, fin_b, out);
}